// Round 1
// baseline (11011.958 us; speedup 1.0000x reference)
//
#include <hip/hip_runtime.h>

#define B_   32
#define N_   716
#define T_   168
#define L_   64
#define NT_  884     // N + T
#define GIN_ 752     // N + SED + TED
#define TE3_ 192     // 3*L
#define TRH_ 716     // tr hidden
#define TR3_ 2148    // 3*TRH

static __device__ __forceinline__ float eluf(float x){ return x > 0.f ? x : expm1f(x); }
static __device__ __forceinline__ float sigf(float x){ return 1.f/(1.f+expf(-x)); }

// ---------------- generic transpose: out[c][r] = in[r][c] ----------------
__global__ __launch_bounds__(256) void k_transpose(const float* __restrict__ in,
                                                   float* __restrict__ out, int R, int C){
  __shared__ float tile[32][33];
  int c0 = blockIdx.x*32, r0 = blockIdx.y*32;
  int tx = threadIdx.x & 31, ty = threadIdx.x >> 5;
  for (int i = ty; i < 32; i += 8){
    int r = r0 + i, c = c0 + tx;
    if (r < R && c < C) tile[i][tx] = in[(size_t)r*C + c];
  }
  __syncthreads();
  for (int i = ty; i < 32; i += 8){
    int c = c0 + i, r = r0 + tx;
    if (c < C && r < R) out[(size_t)c*R + r] = tile[tx][i];
  }
}

// ---------------- SE path: Xs = elu(se_in@W1+b1)@W2+b2 -> X[:, :716, :] ----------------
__global__ __launch_bounds__(64) void k_se(const float* __restrict__ x, const float* __restrict__ se_emb,
                 const float* __restrict__ W1, const float* __restrict__ b1,
                 const float* __restrict__ W2, const float* __restrict__ b2,
                 float* __restrict__ X){
  int bn = blockIdx.x; int b = bn / N_, n = bn % N_;
  int tid = threadIdx.x;
  __shared__ float row[200];
  __shared__ float hid[64];
  for (int i = tid; i < 200; i += 64)
    row[i] = (i < T_) ? x[((size_t)b*N_ + n)*T_ + i] : se_emb[n*32 + (i - T_)];
  __syncthreads();
  float acc = b1[tid];
  for (int k = 0; k < 200; ++k) acc = fmaf(row[k], W1[k*64 + tid], acc);
  hid[tid] = eluf(acc);
  __syncthreads();
  float acc2 = b2[tid];
  for (int k = 0; k < 64; ++k) acc2 = fmaf(hid[k], W2[k*64 + tid], acc2);
  X[((size_t)b*NT_ + n)*L_ + tid] = acc2;
}

// ---------------- te_in construction ----------------
__global__ __launch_bounds__(256) void k_tein_x(const float* __restrict__ x, float* __restrict__ te_in){
  __shared__ float tile[32][33];
  int b = blockIdx.z; int n0 = blockIdx.x*32, t0 = blockIdx.y*32;
  int tx = threadIdx.x & 31, ty = threadIdx.x >> 5;
  for (int i = ty; i < 32; i += 8){
    int n = n0 + i, t = t0 + tx;
    if (n < N_ && t < T_) tile[i][tx] = x[((size_t)b*N_ + n)*T_ + t];
  }
  __syncthreads();
  for (int i = ty; i < 32; i += 8){
    int t = t0 + i, n = n0 + tx;
    if (t < T_ && n < N_) te_in[((size_t)b*T_ + t)*GIN_ + n] = tile[tx][i];
  }
}
__global__ __launch_bounds__(256) void k_tein_rest(const float* __restrict__ mark,
                    const float* __restrict__ te_emb, float* __restrict__ te_in){
  int idx = blockIdx.x*256 + threadIdx.x;
  if (idx >= B_*T_*36) return;
  int c = idx % 36; int row = idx / 36; int b = row / T_, t = row % T_;
  float v = (c < 4) ? mark[((size_t)b*T_ + t)*4 + c] : te_emb[t*32 + (c-4)];
  te_in[(size_t)row*GIN_ + N_ + c] = v;
}

// ---------------- generic tiled GEMM C = A@B + bias ----------------
__global__ __launch_bounds__(256) void k_gemm_bias(const float* __restrict__ A, const float* __restrict__ Bm,
                   const float* __restrict__ bias, float* __restrict__ C,
                   int M, int N, int K){
  __shared__ float As[16][65];
  __shared__ float Bs[16][65];
  int m0 = blockIdx.x*64, n0 = blockIdx.y*64;
  int tid = threadIdx.x;
  int tx = tid & 15, ty = tid >> 4;
  float acc[4][4] = {};
  for (int kt = 0; kt < K; kt += 16){
    for (int l = tid; l < 64*16; l += 256){
      int m = l >> 4, kk = l & 15;
      int gm = m0 + m, gk = kt + kk;
      As[kk][m] = (gm < M && gk < K) ? A[(size_t)gm*K + gk] : 0.f;
    }
    for (int l = tid; l < 16*64; l += 256){
      int kk = l >> 6, n = l & 63;
      int gk = kt + kk, gn = n0 + n;
      Bs[kk][n] = (gk < K && gn < N) ? Bm[(size_t)gk*N + gn] : 0.f;
    }
    __syncthreads();
    #pragma unroll 4
    for (int kk = 0; kk < 16; ++kk){
      float a[4], bb[4];
      #pragma unroll
      for (int i = 0; i < 4; ++i) a[i] = As[kk][ty + 16*i];
      #pragma unroll
      for (int j = 0; j < 4; ++j) bb[j] = Bs[kk][tx + 16*j];
      #pragma unroll
      for (int i = 0; i < 4; ++i)
        #pragma unroll
        for (int j = 0; j < 4; ++j) acc[i][j] = fmaf(a[i], bb[j], acc[i][j]);
    }
    __syncthreads();
  }
  for (int i = 0; i < 4; ++i){
    int gm = m0 + ty + 16*i; if (gm >= M) continue;
    for (int j = 0; j < 4; ++j){
      int gn = n0 + tx + 16*j; if (gn >= N) continue;
      C[(size_t)gm*N + gn] = acc[i][j] + bias[gn];
    }
  }
}

// ---------------- te GRU scan (hidden 64, Whh in LDS), writes X[:, 716:884, :] ----------------
__global__ __launch_bounds__(192) void k_te_scan(const float* __restrict__ xw, const float* __restrict__ Whh,
                 const float* __restrict__ bhh, float* __restrict__ X){
  int b = blockIdx.x; int tid = threadIdx.x;
  __shared__ float Wsh[TE3_*65];
  __shared__ float hs[64];
  __shared__ float gh[TE3_];
  for (int l = tid; l < TE3_*64; l += 192){ int j = l >> 6, f = l & 63; Wsh[j*65+f] = Whh[l]; }
  if (tid < 64) hs[tid] = 0.f;
  __syncthreads();
  for (int t = 0; t < T_; ++t){
    const float* xr = xw + ((size_t)b*T_ + t)*TE3_;
    float g = bhh[tid];
    #pragma unroll 8
    for (int f = 0; f < 64; ++f) g = fmaf(hs[f], Wsh[tid*65+f], g);
    gh[tid] = g;
    __syncthreads();
    if (tid < 64){
      float r = sigf(xr[tid] + gh[tid]);
      float z = sigf(xr[64+tid] + gh[64+tid]);
      float n = tanhf(xr[128+tid] + r*gh[128+tid]);
      float hn = (1.f - z)*n + z*hs[tid];
      hs[tid] = hn;
      X[((size_t)b*NT_ + N_ + t)*L_ + tid] = hn;
    }
    __syncthreads();
  }
}

// ---------------- adjacency: adj = tanh(relu(X@X^T) + I) ----------------
__global__ __launch_bounds__(256) void k_adj(const float* __restrict__ X, float* __restrict__ adj){
  __shared__ float At[32][65];
  __shared__ float Bt[32][65];
  int b = blockIdx.z; int i0 = blockIdx.x*32, j0 = blockIdx.y*32;
  int tid = threadIdx.x;
  for (int l = tid; l < 32*64; l += 256){
    int r = l >> 6, f = l & 63;
    int gi = i0 + r; At[r][f] = (gi < NT_) ? X[((size_t)b*NT_+gi)*L_+f] : 0.f;
    int gj = j0 + r; Bt[r][f] = (gj < NT_) ? X[((size_t)b*NT_+gj)*L_+f] : 0.f;
  }
  __syncthreads();
  int tx = tid & 15, ty = tid >> 4;
  int r0 = 2*ty, c0 = 2*tx;
  float a00=0,a01=0,a10=0,a11=0;
  #pragma unroll 4
  for (int f = 0; f < 64; ++f){
    float x0 = At[r0][f],  x1 = At[r0+1][f];
    float y0 = Bt[c0][f],  y1 = Bt[c0+1][f];
    a00 = fmaf(x0,y0,a00); a01 = fmaf(x0,y1,a01);
    a10 = fmaf(x1,y0,a10); a11 = fmaf(x1,y1,a11);
  }
  int gi0 = i0 + r0, gj0 = j0 + c0;
  #pragma unroll
  for (int ii = 0; ii < 2; ++ii){
    int gi = gi0 + ii; if (gi >= NT_) continue;
    float v0 = ii ? a10 : a00, v1 = ii ? a11 : a01;
    if (gj0 < NT_)   adj[((size_t)b*NT_+gi)*NT_+gj0]   = tanhf(fmaxf(v0,0.f) + (gi==gj0   ? 1.f:0.f));
    if (gj0+1 < NT_) adj[((size_t)b*NT_+gi)*NT_+gj0+1] = tanhf(fmaxf(v1,0.f) + (gi==gj0+1 ? 1.f:0.f));
  }
}

// ---------------- GCN step: Hout = elu((adj@Hin)@W + b) ----------------
__global__ __launch_bounds__(256) void k_gcn(const float* __restrict__ adj, const float* __restrict__ Hin,
                 const float* __restrict__ W, const float* __restrict__ bias,
                 float* __restrict__ Hout){
  __shared__ float Adjt[32][33];
  __shared__ float Ht[32][65];
  __shared__ float Tmp[32][65];
  int b = blockIdx.y; int r0 = blockIdx.x*32;
  int tid = threadIdx.x;
  int f = tid & 63, rq = tid >> 6;
  float acc[8] = {};
  for (int kt = 0; kt < NT_; kt += 32){
    for (int l = tid; l < 32*32; l += 256){
      int r = l >> 5, kk = l & 31;
      int gr = r0 + r, gk = kt + kk;
      Adjt[r][kk] = (gr < NT_ && gk < NT_) ? adj[((size_t)b*NT_+gr)*NT_+gk] : 0.f;
    }
    for (int l = tid; l < 32*64; l += 256){
      int kk = l >> 6, ff = l & 63;
      int gk = kt + kk;
      Ht[kk][ff] = (gk < NT_) ? Hin[((size_t)b*NT_+gk)*L_+ff] : 0.f;
    }
    __syncthreads();
    #pragma unroll 4
    for (int kk = 0; kk < 32; ++kk){
      float hv = Ht[kk][f];
      #pragma unroll
      for (int rr = 0; rr < 8; ++rr)
        acc[rr] = fmaf(Adjt[rq + 4*rr][kk], hv, acc[rr]);
    }
    __syncthreads();
  }
  #pragma unroll
  for (int rr = 0; rr < 8; ++rr) Tmp[rq + 4*rr][f] = acc[rr];
  __syncthreads();
  float out[8];
  #pragma unroll
  for (int rr = 0; rr < 8; ++rr) out[rr] = bias[f];
  #pragma unroll 4
  for (int ff = 0; ff < 64; ++ff){
    float wv = W[ff*64 + f];
    #pragma unroll
    for (int rr = 0; rr < 8; ++rr)
      out[rr] = fmaf(Tmp[rq + 4*rr][ff], wv, out[rr]);
  }
  for (int rr = 0; rr < 8; ++rr){
    int gr = r0 + rq + 4*rr;
    if (gr < NT_) Hout[((size_t)b*NT_+gr)*L_+f] = eluf(out[rr]);
  }
}

// ---------------- fr path: only output cols 160..167 needed ----------------
__global__ __launch_bounds__(192) void k_fr(const float* __restrict__ X, const float* __restrict__ W1,
                const float* __restrict__ b1, const float* __restrict__ W2,
                const float* __restrict__ b2, float* __restrict__ nout8){
  int bn = blockIdx.x; int b = bn / N_, n = bn % N_;
  int tid = threadIdx.x;
  __shared__ float xs[64];
  __shared__ float t1[T_];
  __shared__ float part[24*8];
  if (tid < 64) xs[tid] = X[((size_t)b*NT_+n)*L_+tid];
  __syncthreads();
  if (tid < T_){
    float a = b1[tid];
    #pragma unroll 8
    for (int ff = 0; ff < 64; ++ff) a = fmaf(xs[ff], W1[ff*T_+tid], a);
    t1[tid] = eluf(a);
  }
  __syncthreads();
  int c = tid & 7, p = tid >> 3;
  float s = 0.f;
  for (int ff = p; ff < T_; ff += 24) s = fmaf(t1[ff], W2[ff*T_ + 160 + c], s);
  part[p*8 + c] = s;
  __syncthreads();
  if (tid < 8){
    float a = b2[160 + tid];
    #pragma unroll
    for (int q = 0; q < 24; ++q) a += part[q*8 + tid];
    nout8[((size_t)bn)*8 + tid] = a;
  }
}

// ---------------- gather Xt into (T, B, 64) layout ----------------
__global__ __launch_bounds__(256) void k_xtbuf(const float* __restrict__ X, float* __restrict__ XtBuf){
  int idx = blockIdx.x*256 + threadIdx.x;
  if (idx >= T_*B_*L_) return;
  int f = idx & 63; int tb = idx >> 6; int bb = tb & 31; int t = tb >> 5;
  XtBuf[idx] = X[((size_t)bb*NT_ + N_ + t)*L_ + f];
}

// ---------------- tr GRU single step ----------------
__global__ __launch_bounds__(256) void k_tr_step(
    const float* __restrict__ XtBuf, const float* __restrict__ WihT,
    const float* __restrict__ WhhT, const float* __restrict__ bih, const float* __restrict__ bhh,
    const float* __restrict__ hprev, float* __restrict__ hnext,
    float* __restrict__ tout8, int t){
  __shared__ float xts[32*65];
  __shared__ float wih_s[64*24];
  __shared__ float ws[128*24];
  __shared__ float hs2[128*32];
  int tid = threadIdx.x;
  int b = tid & 31, kk = tid >> 5;
  int k0 = blockIdx.x*8;
  int k = k0 + kk;
  for (int l = tid; l < 32*64; l += 256){ int bb = l >> 6, f = l & 63; xts[bb*65+f] = XtBuf[(size_t)t*32*64 + l]; }
  for (int l = tid; l < 64*24; l += 256){
    int ff = l / 24, c = l % 24; int g = c >> 3, k2 = k0 + (c & 7);
    wih_s[l] = (k2 < TRH_) ? WihT[(size_t)ff*TR3_ + g*TRH_ + k2] : 0.f;
  }
  __syncthreads();
  int kc = (k < TRH_) ? k : 0;
  float ir = bih[kc], iz = bih[TRH_+kc], in_ = bih[2*TRH_+kc];
  {
    float ar=0.f, az=0.f, an=0.f;
    #pragma unroll 4
    for (int ff = 0; ff < 64; ++ff){
      float xv = xts[b*65+ff];
      ar = fmaf(xv, wih_s[ff*24 + kk], ar);
      az = fmaf(xv, wih_s[ff*24 + 8 + kk], az);
      an = fmaf(xv, wih_s[ff*24 + 16 + kk], an);
    }
    ir += ar; iz += az; in_ += an;
  }
  float gr = 0.f, gz = 0.f, gn = 0.f;
  for (int jt = 0; jt < TRH_; jt += 128){
    int jc = min(128, TRH_ - jt);
    __syncthreads();
    for (int l = tid; l < jc*32; l += 256) hs2[l] = hprev[(size_t)jt*32 + l];
    for (int l = tid; l < jc*24; l += 256){
      int jj = l / 24, c = l % 24; int g = c >> 3, k2 = k0 + (c & 7);
      ws[l] = (k2 < TRH_) ? WhhT[(size_t)(jt+jj)*TR3_ + g*TRH_ + k2] : 0.f;
    }
    __syncthreads();
    #pragma unroll 4
    for (int jj = 0; jj < jc; ++jj){
      float hv = hs2[jj*32 + b];
      gr = fmaf(hv, ws[jj*24 + kk], gr);
      gz = fmaf(hv, ws[jj*24 + 8 + kk], gz);
      gn = fmaf(hv, ws[jj*24 + 16 + kk], gn);
    }
  }
  if (k < TRH_){
    gr += bhh[k]; gz += bhh[TRH_+k]; gn += bhh[2*TRH_+k];
    float hp = hprev[k*32 + b];
    float r = sigf(ir + gr);
    float z = sigf(iz + gz);
    float nn = tanhf(in_ + r*gn);
    float hn = (1.f - z)*nn + z*hp;
    hnext[k*32 + b] = hn;
    if (t >= 160) tout8[((size_t)b*N_ + k)*8 + (t-160)] = hn;
  }
}

// ---------------- fused TCN tail (only t=167 of final output) ----------------
__global__ __launch_bounds__(256) void k_tcn(const float* __restrict__ nout8, const float* __restrict__ tout8,
                 const float* __restrict__ x,
                 const float* __restrict__ W0, const float* __restrict__ b0,
                 const float* __restrict__ W1, const float* __restrict__ b1,
                 const float* __restrict__ W2, const float* __restrict__ b2,
                 const float* __restrict__ oW, const float* __restrict__ ob,
                 float* __restrict__ out){
  __shared__ float w0s[96], b0s[16], w1s[512], b1s[16], w2s[512], b2s[16], ows[16], obs;
  int tid = threadIdx.x;
  for (int l = tid; l < 96; l += 256) w0s[l] = W0[l];
  for (int l = tid; l < 512; l += 256){ w1s[l] = W1[l]; w2s[l] = W2[l]; }
  if (tid < 16){ b0s[tid]=b0[tid]; b1s[tid]=b1[tid]; b2s[tid]=b2[tid]; ows[tid]=oW[tid]; }
  if (tid == 0) obs = ob[0];
  __syncthreads();
  int idx = blockIdx.x*256 + tid;
  if (idx >= B_*N_) return;
  int b = idx / N_, n = idx % N_;
  float s0[8], s1[8], s2[8];
  #pragma unroll
  for (int i = 0; i < 8; ++i){
    s0[i] = nout8[(size_t)idx*8 + i];
    s1[i] = tout8[(size_t)idx*8 + i];
    s2[i] = x[((size_t)b*N_ + n)*T_ + 160 + i];
  }
  float h1[16][4];
  #pragma unroll
  for (int c = 0; c < 16; ++c)
    #pragma unroll
    for (int q = 0; q < 4; ++q){
      int tt = 2*q + 1;
      float v = b0s[c]
        + w0s[c*6+0]*s0[tt-1] + w0s[c*6+1]*s0[tt]
        + w0s[c*6+2]*s1[tt-1] + w0s[c*6+3]*s1[tt]
        + w0s[c*6+4]*s2[tt-1] + w0s[c*6+5]*s2[tt];
      h1[c][q] = eluf(v);
    }
  float h2[16][2];
  #pragma unroll
  for (int c = 0; c < 16; ++c){
    float v3 = b1s[c], v7 = b1s[c];
    #pragma unroll
    for (int i2 = 0; i2 < 16; ++i2){
      v3 += w1s[c*32+i2*2]*h1[i2][0] + w1s[c*32+i2*2+1]*h1[i2][1];
      v7 += w1s[c*32+i2*2]*h1[i2][2] + w1s[c*32+i2*2+1]*h1[i2][3];
    }
    h2[c][0] = eluf(v3); h2[c][1] = eluf(v7);
  }
  float o = obs;
  #pragma unroll
  for (int c = 0; c < 16; ++c){
    float v = b2s[c];
    #pragma unroll
    for (int i2 = 0; i2 < 16; ++i2)
      v += w2s[c*32+i2*2]*h2[i2][0] + w2s[c*32+i2*2+1]*h2[i2][1];
    o += ows[c]*eluf(v);
  }
  out[idx] = o;
}

extern "C" void kernel_launch(void* const* d_in, const int* in_sizes, int n_in,
                              void* d_out, int out_size, void* d_ws, size_t ws_size,
                              hipStream_t stream){
  const float* x       = (const float*)d_in[0];
  const float* mark    = (const float*)d_in[1];
  const float* se_emb  = (const float*)d_in[2];
  const float* se_W1   = (const float*)d_in[3];
  const float* se_b1   = (const float*)d_in[4];
  const float* se_W2   = (const float*)d_in[5];
  const float* se_b2   = (const float*)d_in[6];
  const float* te_emb  = (const float*)d_in[7];
  const float* te_Wih  = (const float*)d_in[8];
  const float* te_Whh  = (const float*)d_in[9];
  const float* te_bih  = (const float*)d_in[10];
  const float* te_bhh  = (const float*)d_in[11];
  const float* gcn_W   = (const float*)d_in[12];
  const float* gcn_b   = (const float*)d_in[13];
  const float* fr_W1   = (const float*)d_in[14];
  const float* fr_b1   = (const float*)d_in[15];
  const float* fr_W2   = (const float*)d_in[16];
  const float* fr_b2   = (const float*)d_in[17];
  const float* tr_Wih  = (const float*)d_in[18];
  const float* tr_Whh  = (const float*)d_in[19];
  const float* tr_bih  = (const float*)d_in[20];
  const float* tr_bhh  = (const float*)d_in[21];
  const float* tcn_W0  = (const float*)d_in[22];
  const float* tcn_b0  = (const float*)d_in[23];
  const float* tcn_W1  = (const float*)d_in[24];
  const float* tcn_b1  = (const float*)d_in[25];
  const float* tcn_W2  = (const float*)d_in[26];
  const float* tcn_b2  = (const float*)d_in[27];
  const float* out_W   = (const float*)d_in[28];
  const float* out_b   = (const float*)d_in[29];
  float* out = (float*)d_out;
  (void)in_sizes; (void)n_in; (void)out_size; (void)ws_size;

  char* ws = (char*)d_ws;
  size_t off = 0;
  auto alloc = [&](size_t bytes)->float*{
    float* p = (float*)(ws + off); off += (bytes + 255) & ~(size_t)255; return p; };
  float* X       = alloc((size_t)B_*NT_*L_*4);
  float* adj     = alloc((size_t)B_*NT_*NT_*4);
  float* Xtmp    = alloc((size_t)B_*NT_*L_*4);
  float* te_in   = alloc((size_t)B_*T_*GIN_*4);
  float* te_xw   = alloc((size_t)B_*T_*TE3_*4);
  float* WihT_te = alloc((size_t)GIN_*TE3_*4);
  float* WihT_tr = alloc((size_t)L_*TR3_*4);
  float* WhhT_tr = alloc((size_t)TRH_*TR3_*4);
  float* XtBuf   = alloc((size_t)T_*B_*L_*4);
  float* hA      = alloc((size_t)TRH_*B_*4);
  float* hB      = alloc((size_t)TRH_*B_*4);
  float* nout8   = alloc((size_t)B_*N_*8*4);
  float* tout8   = alloc((size_t)B_*N_*8*4);

  // weight transposes
  k_transpose<<<dim3(24,6),256,0,stream>>>(te_Wih, WihT_te, TE3_, GIN_);
  k_transpose<<<dim3(2,68),256,0,stream>>>(tr_Wih, WihT_tr, TR3_, L_);
  k_transpose<<<dim3(23,68),256,0,stream>>>(tr_Whh, WhhT_tr, TR3_, TRH_);
  // SE path
  k_se<<<B_*N_,64,0,stream>>>(x, se_emb, se_W1, se_b1, se_W2, se_b2, X);
  // te path
  k_tein_x<<<dim3(23,6,B_),256,0,stream>>>(x, te_in);
  k_tein_rest<<<(B_*T_*36+255)/256,256,0,stream>>>(mark, te_emb, te_in);
  k_gemm_bias<<<dim3(84,3),256,0,stream>>>(te_in, WihT_te, te_bih, te_xw, B_*T_, TE3_, GIN_);
  k_te_scan<<<B_,192,0,stream>>>(te_xw, te_Whh, te_bhh, X);
  // GCN
  for (int i = 0; i < 2; ++i){
    k_adj<<<dim3(28,28,B_),256,0,stream>>>(X, adj);
    k_gcn<<<dim3(28,B_),256,0,stream>>>(adj, X,    gcn_W + (i*2+0)*4096, gcn_b + (i*2+0)*64, Xtmp);
    k_gcn<<<dim3(28,B_),256,0,stream>>>(adj, Xtmp, gcn_W + (i*2+1)*4096, gcn_b + (i*2+1)*64, X);
  }
  // fr path (last 8 cols only)
  k_fr<<<B_*N_,192,0,stream>>>(X, fr_W1, fr_b1, fr_W2, fr_b2, nout8);
  // tr GRU
  k_xtbuf<<<(T_*B_*L_+255)/256,256,0,stream>>>(X, XtBuf);
  hipMemsetAsync(hA, 0, (size_t)TRH_*B_*4, stream);
  for (int t = 0; t < T_; ++t){
    const float* hp = (t & 1) ? hB : hA;
    float*       hn = (t & 1) ? hA : hB;
    k_tr_step<<<90,256,0,stream>>>(XtBuf, WihT_tr, WhhT_tr, tr_bih, tr_bhh, hp, hn, tout8, t);
  }
  // fused TCN tail
  k_tcn<<<(B_*N_+255)/256,256,0,stream>>>(nout8, tout8, x,
      tcn_W0, tcn_b0, tcn_W1, tcn_b1, tcn_W2, tcn_b2, out_W, out_b, out);
}

// Round 2
// 3262.987 us; speedup vs baseline: 3.3748x; 3.3748x over previous
//
#include <hip/hip_runtime.h>

#define B_   32
#define N_   716
#define T_   168
#define L_   64
#define NT_  884     // N + T
#define GIN_ 752     // N + SED + TED
#define TE3_ 192     // 3*L
#define TRH_ 716     // tr hidden
#define TR3_ 2148    // 3*TRH
#define WSTR 744     // padded bf16 row stride in LDS (4-way bank spread, 16B aligned)
#define TRBLKS 90    // 45 col-blocks x 2 batch halves

typedef unsigned short u16;
typedef __attribute__((ext_vector_type(8))) short short8;
typedef __attribute__((ext_vector_type(4))) float f32x4;

static __device__ __forceinline__ float eluf(float x){ return x > 0.f ? x : expm1f(x); }
static __device__ __forceinline__ float sigf(float x){ return 1.f/(1.f+expf(-x)); }
static __device__ __forceinline__ u16 f2bf(float f){
  unsigned u = __float_as_uint(f);
  unsigned r = (u + 0x7fffu + ((u >> 16) & 1u)) >> 16;
  return (u16)r;
}

// ---------------- generic transpose: out[c][r] = in[r][c] ----------------
__global__ __launch_bounds__(256) void k_transpose(const float* __restrict__ in,
                                                   float* __restrict__ out, int R, int C){
  __shared__ float tile[32][33];
  int c0 = blockIdx.x*32, r0 = blockIdx.y*32;
  int tx = threadIdx.x & 31, ty = threadIdx.x >> 5;
  for (int i = ty; i < 32; i += 8){
    int r = r0 + i, c = c0 + tx;
    if (r < R && c < C) tile[i][tx] = in[(size_t)r*C + c];
  }
  __syncthreads();
  for (int i = ty; i < 32; i += 8){
    int c = c0 + i, r = r0 + tx;
    if (c < C && r < R) out[(size_t)c*R + r] = tile[tx][i];
  }
}

// ---------------- SE path ----------------
__global__ __launch_bounds__(64) void k_se(const float* __restrict__ x, const float* __restrict__ se_emb,
                 const float* __restrict__ W1, const float* __restrict__ b1,
                 const float* __restrict__ W2, const float* __restrict__ b2,
                 float* __restrict__ X){
  int bn = blockIdx.x; int b = bn / N_, n = bn % N_;
  int tid = threadIdx.x;
  __shared__ float row[200];
  __shared__ float hid[64];
  for (int i = tid; i < 200; i += 64)
    row[i] = (i < T_) ? x[((size_t)b*N_ + n)*T_ + i] : se_emb[n*32 + (i - T_)];
  __syncthreads();
  float acc = b1[tid];
  for (int k = 0; k < 200; ++k) acc = fmaf(row[k], W1[k*64 + tid], acc);
  hid[tid] = eluf(acc);
  __syncthreads();
  float acc2 = b2[tid];
  for (int k = 0; k < 64; ++k) acc2 = fmaf(hid[k], W2[k*64 + tid], acc2);
  X[((size_t)b*NT_ + n)*L_ + tid] = acc2;
}

// ---------------- te_in construction ----------------
__global__ __launch_bounds__(256) void k_tein_x(const float* __restrict__ x, float* __restrict__ te_in){
  __shared__ float tile[32][33];
  int b = blockIdx.z; int n0 = blockIdx.x*32, t0 = blockIdx.y*32;
  int tx = threadIdx.x & 31, ty = threadIdx.x >> 5;
  for (int i = ty; i < 32; i += 8){
    int n = n0 + i, t = t0 + tx;
    if (n < N_ && t < T_) tile[i][tx] = x[((size_t)b*N_ + n)*T_ + t];
  }
  __syncthreads();
  for (int i = ty; i < 32; i += 8){
    int t = t0 + i, n = n0 + tx;
    if (t < T_ && n < N_) te_in[((size_t)b*T_ + t)*GIN_ + n] = tile[tx][i];
  }
}
__global__ __launch_bounds__(256) void k_tein_rest(const float* __restrict__ mark,
                    const float* __restrict__ te_emb, float* __restrict__ te_in){
  int idx = blockIdx.x*256 + threadIdx.x;
  if (idx >= B_*T_*36) return;
  int c = idx % 36; int row = idx / 36; int b = row / T_, t = row % T_;
  float v = (c < 4) ? mark[((size_t)b*T_ + t)*4 + c] : te_emb[t*32 + (c-4)];
  te_in[(size_t)row*GIN_ + N_ + c] = v;
}

// ---------------- generic tiled GEMM C = A@B + bias ----------------
__global__ __launch_bounds__(256) void k_gemm_bias(const float* __restrict__ A, const float* __restrict__ Bm,
                   const float* __restrict__ bias, float* __restrict__ C,
                   int M, int N, int K){
  __shared__ float As[16][65];
  __shared__ float Bs[16][65];
  int m0 = blockIdx.x*64, n0 = blockIdx.y*64;
  int tid = threadIdx.x;
  int tx = tid & 15, ty = tid >> 4;
  float acc[4][4] = {};
  for (int kt = 0; kt < K; kt += 16){
    for (int l = tid; l < 64*16; l += 256){
      int m = l >> 4, kk = l & 15;
      int gm = m0 + m, gk = kt + kk;
      As[kk][m] = (gm < M && gk < K) ? A[(size_t)gm*K + gk] : 0.f;
    }
    for (int l = tid; l < 16*64; l += 256){
      int kk = l >> 6, n = l & 63;
      int gk = kt + kk, gn = n0 + n;
      Bs[kk][n] = (gk < K && gn < N) ? Bm[(size_t)gk*N + gn] : 0.f;
    }
    __syncthreads();
    #pragma unroll 4
    for (int kk = 0; kk < 16; ++kk){
      float a[4], bb[4];
      #pragma unroll
      for (int i = 0; i < 4; ++i) a[i] = As[kk][ty + 16*i];
      #pragma unroll
      for (int j = 0; j < 4; ++j) bb[j] = Bs[kk][tx + 16*j];
      #pragma unroll
      for (int i = 0; i < 4; ++i)
        #pragma unroll
        for (int j = 0; j < 4; ++j) acc[i][j] = fmaf(a[i], bb[j], acc[i][j]);
    }
    __syncthreads();
  }
  for (int i = 0; i < 4; ++i){
    int gm = m0 + ty + 16*i; if (gm >= M) continue;
    for (int j = 0; j < 4; ++j){
      int gn = n0 + tx + 16*j; if (gn >= N) continue;
      C[(size_t)gm*N + gn] = acc[i][j] + bias[gn];
    }
  }
}

// ---------------- te GRU scan ----------------
__global__ __launch_bounds__(192) void k_te_scan(const float* __restrict__ xw, const float* __restrict__ Whh,
                 const float* __restrict__ bhh, float* __restrict__ X){
  int b = blockIdx.x; int tid = threadIdx.x;
  __shared__ float Wsh[TE3_*65];
  __shared__ float hs[64];
  __shared__ float gh[TE3_];
  for (int l = tid; l < TE3_*64; l += 192){ int j = l >> 6, f = l & 63; Wsh[j*65+f] = Whh[l]; }
  if (tid < 64) hs[tid] = 0.f;
  __syncthreads();
  for (int t = 0; t < T_; ++t){
    const float* xr = xw + ((size_t)b*T_ + t)*TE3_;
    float g = bhh[tid];
    #pragma unroll 8
    for (int f = 0; f < 64; ++f) g = fmaf(hs[f], Wsh[tid*65+f], g);
    gh[tid] = g;
    __syncthreads();
    if (tid < 64){
      float r = sigf(xr[tid] + gh[tid]);
      float z = sigf(xr[64+tid] + gh[64+tid]);
      float n = tanhf(xr[128+tid] + r*gh[128+tid]);
      float hn = (1.f - z)*n + z*hs[tid];
      hs[tid] = hn;
      X[((size_t)b*NT_ + N_ + t)*L_ + tid] = hn;
    }
    __syncthreads();
  }
}

// ---------------- adjacency ----------------
__global__ __launch_bounds__(256) void k_adj(const float* __restrict__ X, float* __restrict__ adj){
  __shared__ float At[32][65];
  __shared__ float Bt[32][65];
  int b = blockIdx.z; int i0 = blockIdx.x*32, j0 = blockIdx.y*32;
  int tid = threadIdx.x;
  for (int l = tid; l < 32*64; l += 256){
    int r = l >> 6, f = l & 63;
    int gi = i0 + r; At[r][f] = (gi < NT_) ? X[((size_t)b*NT_+gi)*L_+f] : 0.f;
    int gj = j0 + r; Bt[r][f] = (gj < NT_) ? X[((size_t)b*NT_+gj)*L_+f] : 0.f;
  }
  __syncthreads();
  int tx = tid & 15, ty = tid >> 4;
  int r0 = 2*ty, c0 = 2*tx;
  float a00=0,a01=0,a10=0,a11=0;
  #pragma unroll 4
  for (int f = 0; f < 64; ++f){
    float x0 = At[r0][f],  x1 = At[r0+1][f];
    float y0 = Bt[c0][f],  y1 = Bt[c0+1][f];
    a00 = fmaf(x0,y0,a00); a01 = fmaf(x0,y1,a01);
    a10 = fmaf(x1,y0,a10); a11 = fmaf(x1,y1,a11);
  }
  int gi0 = i0 + r0, gj0 = j0 + c0;
  #pragma unroll
  for (int ii = 0; ii < 2; ++ii){
    int gi = gi0 + ii; if (gi >= NT_) continue;
    float v0 = ii ? a10 : a00, v1 = ii ? a11 : a01;
    if (gj0 < NT_)   adj[((size_t)b*NT_+gi)*NT_+gj0]   = tanhf(fmaxf(v0,0.f) + (gi==gj0   ? 1.f:0.f));
    if (gj0+1 < NT_) adj[((size_t)b*NT_+gi)*NT_+gj0+1] = tanhf(fmaxf(v1,0.f) + (gi==gj0+1 ? 1.f:0.f));
  }
}

// ---------------- GCN step ----------------
__global__ __launch_bounds__(256) void k_gcn(const float* __restrict__ adj, const float* __restrict__ Hin,
                 const float* __restrict__ W, const float* __restrict__ bias,
                 float* __restrict__ Hout){
  __shared__ float Adjt[32][33];
  __shared__ float Ht[32][65];
  __shared__ float Tmp[32][65];
  int b = blockIdx.y; int r0 = blockIdx.x*32;
  int tid = threadIdx.x;
  int f = tid & 63, rq = tid >> 6;
  float acc[8] = {};
  for (int kt = 0; kt < NT_; kt += 32){
    for (int l = tid; l < 32*32; l += 256){
      int r = l >> 5, kk = l & 31;
      int gr = r0 + r, gk = kt + kk;
      Adjt[r][kk] = (gr < NT_ && gk < NT_) ? adj[((size_t)b*NT_+gr)*NT_+gk] : 0.f;
    }
    for (int l = tid; l < 32*64; l += 256){
      int kk = l >> 6, ff = l & 63;
      int gk = kt + kk;
      Ht[kk][ff] = (gk < NT_) ? Hin[((size_t)b*NT_+gk)*L_+ff] : 0.f;
    }
    __syncthreads();
    #pragma unroll 4
    for (int kk = 0; kk < 32; ++kk){
      float hv = Ht[kk][f];
      #pragma unroll
      for (int rr = 0; rr < 8; ++rr)
        acc[rr] = fmaf(Adjt[rq + 4*rr][kk], hv, acc[rr]);
    }
    __syncthreads();
  }
  #pragma unroll
  for (int rr = 0; rr < 8; ++rr) Tmp[rq + 4*rr][f] = acc[rr];
  __syncthreads();
  float out[8];
  #pragma unroll
  for (int rr = 0; rr < 8; ++rr) out[rr] = bias[f];
  #pragma unroll 4
  for (int ff = 0; ff < 64; ++ff){
    float wv = W[ff*64 + f];
    #pragma unroll
    for (int rr = 0; rr < 8; ++rr)
      out[rr] = fmaf(Tmp[rq + 4*rr][ff], wv, out[rr]);
  }
  for (int rr = 0; rr < 8; ++rr){
    int gr = r0 + rq + 4*rr;
    if (gr < NT_) Hout[((size_t)b*NT_+gr)*L_+f] = eluf(out[rr]);
  }
}

// ---------------- fr path: only output cols 160..167 needed ----------------
__global__ __launch_bounds__(192) void k_fr(const float* __restrict__ X, const float* __restrict__ W1,
                const float* __restrict__ b1, const float* __restrict__ W2,
                const float* __restrict__ b2, float* __restrict__ nout8){
  int bn = blockIdx.x; int b = bn / N_, n = bn % N_;
  int tid = threadIdx.x;
  __shared__ float xs[64];
  __shared__ float t1[T_];
  __shared__ float part[24*8];
  if (tid < 64) xs[tid] = X[((size_t)b*NT_+n)*L_+tid];
  __syncthreads();
  if (tid < T_){
    float a = b1[tid];
    #pragma unroll 8
    for (int ff = 0; ff < 64; ++ff) a = fmaf(xs[ff], W1[ff*T_+tid], a);
    t1[tid] = eluf(a);
  }
  __syncthreads();
  int c = tid & 7, p = tid >> 3;
  float s = 0.f;
  for (int ff = p; ff < T_; ff += 24) s = fmaf(t1[ff], W2[ff*T_ + 160 + c], s);
  part[p*8 + c] = s;
  __syncthreads();
  if (tid < 8){
    float a = b2[160 + tid];
    #pragma unroll
    for (int q = 0; q < 24; ++q) a += part[q*8 + tid];
    nout8[((size_t)bn)*8 + tid] = a;
  }
}

// ---------------- gather Xt into (T, B, 64) layout ----------------
__global__ __launch_bounds__(256) void k_xtbuf(const float* __restrict__ X, float* __restrict__ XtBuf){
  int idx = blockIdx.x*256 + threadIdx.x;
  if (idx >= T_*B_*L_) return;
  int f = idx & 63; int tb = idx >> 6; int bb = tb & 31; int t = tb >> 5;
  XtBuf[idx] = X[((size_t)bb*NT_ + N_ + t)*L_ + f];
}

// ---------------- persistent MFMA tr-GRU scan ----------------
// 90 blocks = 45 k-slices (16 k each) x 2 batch halves (16 b each).
// Weights bf16-resident in LDS for all 168 steps. Per step:
//   stage h(bf16) -> LDS, MFMA (wave=gate), cross-wave gate exchange,
//   wave0 computes fp32 gates + h_next, device-scope barrier.
__global__ __launch_bounds__(192) void k_tr_scan(
    const float* __restrict__ Whh,   // (2148, 716) row-major
    const float* __restrict__ bhh,   // (2148)
    const float* __restrict__ xw,    // (5376, 2148): row = t*32+b, includes bih
    float* __restrict__ hm,          // fp32 h master (32, 716)
    u16* __restrict__ hb0, u16* __restrict__ hb1,  // bf16 h ping-pong (32, 716)
    float* __restrict__ tout8,       // (32, 716, 8)
    unsigned* __restrict__ cnt){
  __shared__ u16 w_lds[48*WSTR];
  __shared__ u16 h_lds[16*WSTR];
  __shared__ float g_lds[2*256];
  const int tid = threadIdx.x;
  const int wv = tid >> 6, lane = tid & 63;
  const int cb = blockIdx.x >> 1, hhalf = blockIdx.x & 1;
  const int k0 = cb*16, b0 = hhalf*16;

  // ---- stage weights once: rows r = gate*16 + m  <->  Whh row gate*716 + (k0+m)
  for (int r = 0; r < 48; ++r){
    int g = r >> 4, m = r & 15, k = k0 + m;
    const float* src = Whh + (size_t)(g*TRH_ + (k < TRH_ ? k : 0))*TRH_;
    float mul = (k < TRH_) ? 1.f : 0.f;
    for (int j = tid; j < TRH_; j += 192)
      w_lds[r*WSTR + j] = f2bf(src[j]*mul);
    for (int j = TRH_ + tid; j < WSTR; j += 192) w_lds[r*WSTR + j] = 0;
  }
  for (int n = 0; n < 16; ++n)
    for (int j = TRH_ + tid; j < WSTR; j += 192) h_lds[n*WSTR + j] = 0;

  const u16* arow = w_lds + (size_t)(wv*16 + (lane & 15))*WSTR + (lane >> 4)*8;
  const u16* brow = h_lds + (size_t)(lane & 15)*WSTR + (lane >> 4)*8;

  for (int t = 0; t < T_; ++t){
    const u16* __restrict__ hcur = (t & 1) ? hb1 : hb0;
    u16* __restrict__ hnxt = (t & 1) ? hb0 : hb1;
    // stage h slice (16 batches x 716 bf16) into LDS, 8B chunks
    for (int n = 0; n < 16; ++n){
      const uint2* src = (const uint2*)(hcur + (size_t)(b0 + n)*TRH_);
      uint2* dst = (uint2*)(h_lds + n*WSTR);
      for (int o = tid; o < 179; o += 192) dst[o] = src[o];
    }
    __syncthreads();
    // MFMA accumulate over K=716 (23 tiles of 32, zero-padded to 736)
    f32x4 acc = {0.f, 0.f, 0.f, 0.f};
    for (int kt = 0; kt < 23; ++kt){
      short8 a = *(const short8*)(arow + kt*32);
      short8 b = *(const short8*)(brow + kt*32);
      acc = __builtin_amdgcn_mfma_f32_16x16x32_bf16(a, b, acc, 0, 0, 0);
    }
    // exchange gates z,n to wave 0
    if (wv){
      #pragma unroll
      for (int r = 0; r < 4; ++r) g_lds[(wv-1)*256 + lane*4 + r] = acc[r];
    }
    __syncthreads();
    if (wv == 0){
      const int mb = (lane >> 4)*4;
      const int kx = k0 + mb;
      const bool kval = (kx < TRH_);
      const int kc = kval ? kx : 0;
      const int bx = b0 + (lane & 15);
      const float* xwrow = xw + (size_t)(t*32 + bx)*TR3_;
      f32x4 xr = *(const f32x4*)(xwrow + kc);
      f32x4 xz = *(const f32x4*)(xwrow + TRH_ + kc);
      f32x4 xn = *(const f32x4*)(xwrow + 2*TRH_ + kc);
      f32x4 br = *(const f32x4*)(bhh + kc);
      f32x4 bz = *(const f32x4*)(bhh + TRH_ + kc);
      f32x4 bn = *(const f32x4*)(bhh + 2*TRH_ + kc);
      f32x4 hp = *(const f32x4*)(hm + (size_t)bx*TRH_ + kc);
      float hnew[4];
      #pragma unroll
      for (int r = 0; r < 4; ++r){
        float rg = sigf(xr[r] + acc[r] + br[r]);
        float zg = sigf(xz[r] + g_lds[lane*4 + r] + bz[r]);
        float ng = tanhf(xn[r] + rg*(g_lds[256 + lane*4 + r] + bn[r]));
        hnew[r] = (1.f - zg)*ng + zg*hp[r];
      }
      if (kval){
        f32x4 hv = {hnew[0], hnew[1], hnew[2], hnew[3]};
        *(f32x4*)(hm + (size_t)bx*TRH_ + kx) = hv;
        uint2 pk;
        pk.x = (unsigned)f2bf(hnew[0]) | ((unsigned)f2bf(hnew[1]) << 16);
        pk.y = (unsigned)f2bf(hnew[2]) | ((unsigned)f2bf(hnew[3]) << 16);
        *(uint2*)(hnxt + (size_t)bx*TRH_ + kx) = pk;
        if (t >= 160){
          #pragma unroll
          for (int r = 0; r < 4; ++r)
            tout8[(size_t)(bx*TRH_ + kx + r)*8 + (t - 160)] = hnew[r];
        }
      }
      __threadfence();   // make this wave's global stores device-visible
    }
    __syncthreads();
    // grid barrier (all 90 blocks co-resident: 96KB LDS -> 1 block/CU, 90 < 256 CUs)
    if (tid == 0){
      __hip_atomic_fetch_add(cnt, 1u, __ATOMIC_RELEASE, __HIP_MEMORY_SCOPE_AGENT);
      unsigned tgt = (unsigned)TRBLKS*(t + 1);
      while (__hip_atomic_load(cnt, __ATOMIC_ACQUIRE, __HIP_MEMORY_SCOPE_AGENT) < tgt){}
    }
    __syncthreads();
  }
}

// ---------------- fused TCN tail ----------------
__global__ __launch_bounds__(256) void k_tcn(const float* __restrict__ nout8, const float* __restrict__ tout8,
                 const float* __restrict__ x,
                 const float* __restrict__ W0, const float* __restrict__ b0,
                 const float* __restrict__ W1, const float* __restrict__ b1,
                 const float* __restrict__ W2, const float* __restrict__ b2,
                 const float* __restrict__ oW, const float* __restrict__ ob,
                 float* __restrict__ out){
  __shared__ float w0s[96], b0s[16], w1s[512], b1s[16], w2s[512], b2s[16], ows[16], obs;
  int tid = threadIdx.x;
  for (int l = tid; l < 96; l += 256) w0s[l] = W0[l];
  for (int l = tid; l < 512; l += 256){ w1s[l] = W1[l]; w2s[l] = W2[l]; }
  if (tid < 16){ b0s[tid]=b0[tid]; b1s[tid]=b1[tid]; b2s[tid]=b2[tid]; ows[tid]=oW[tid]; }
  if (tid == 0) obs = ob[0];
  __syncthreads();
  int idx = blockIdx.x*256 + tid;
  if (idx >= B_*N_) return;
  int b = idx / N_, n = idx % N_;
  float s0[8], s1[8], s2[8];
  #pragma unroll
  for (int i = 0; i < 8; ++i){
    s0[i] = nout8[(size_t)idx*8 + i];
    s1[i] = tout8[(size_t)idx*8 + i];
    s2[i] = x[((size_t)b*N_ + n)*T_ + 160 + i];
  }
  float h1[16][4];
  #pragma unroll
  for (int c = 0; c < 16; ++c)
    #pragma unroll
    for (int q = 0; q < 4; ++q){
      int tt = 2*q + 1;
      float v = b0s[c]
        + w0s[c*6+0]*s0[tt-1] + w0s[c*6+1]*s0[tt]
        + w0s[c*6+2]*s1[tt-1] + w0s[c*6+3]*s1[tt]
        + w0s[c*6+4]*s2[tt-1] + w0s[c*6+5]*s2[tt];
      h1[c][q] = eluf(v);
    }
  float h2[16][2];
  #pragma unroll
  for (int c = 0; c < 16; ++c){
    float v3 = b1s[c], v7 = b1s[c];
    #pragma unroll
    for (int i2 = 0; i2 < 16; ++i2){
      v3 += w1s[c*32+i2*2]*h1[i2][0] + w1s[c*32+i2*2+1]*h1[i2][1];
      v7 += w1s[c*32+i2*2]*h1[i2][2] + w1s[c*32+i2*2+1]*h1[i2][3];
    }
    h2[c][0] = eluf(v3); h2[c][1] = eluf(v7);
  }
  float o = obs;
  #pragma unroll
  for (int c = 0; c < 16; ++c){
    float v = b2s[c];
    #pragma unroll
    for (int i2 = 0; i2 < 16; ++i2)
      v += w2s[c*32+i2*2]*h2[i2][0] + w2s[c*32+i2*2+1]*h2[i2][1];
    o += ows[c]*eluf(v);
  }
  out[idx] = o;
}

extern "C" void kernel_launch(void* const* d_in, const int* in_sizes, int n_in,
                              void* d_out, int out_size, void* d_ws, size_t ws_size,
                              hipStream_t stream){
  const float* x       = (const float*)d_in[0];
  const float* mark    = (const float*)d_in[1];
  const float* se_emb  = (const float*)d_in[2];
  const float* se_W1   = (const float*)d_in[3];
  const float* se_b1   = (const float*)d_in[4];
  const float* se_W2   = (const float*)d_in[5];
  const float* se_b2   = (const float*)d_in[6];
  const float* te_emb  = (const float*)d_in[7];
  const float* te_Wih  = (const float*)d_in[8];
  const float* te_Whh  = (const float*)d_in[9];
  const float* te_bih  = (const float*)d_in[10];
  const float* te_bhh  = (const float*)d_in[11];
  const float* gcn_W   = (const float*)d_in[12];
  const float* gcn_b   = (const float*)d_in[13];
  const float* fr_W1   = (const float*)d_in[14];
  const float* fr_b1   = (const float*)d_in[15];
  const float* fr_W2   = (const float*)d_in[16];
  const float* fr_b2   = (const float*)d_in[17];
  const float* tr_Wih  = (const float*)d_in[18];
  const float* tr_Whh  = (const float*)d_in[19];
  const float* tr_bih  = (const float*)d_in[20];
  const float* tr_bhh  = (const float*)d_in[21];
  const float* tcn_W0  = (const float*)d_in[22];
  const float* tcn_b0  = (const float*)d_in[23];
  const float* tcn_W1  = (const float*)d_in[24];
  const float* tcn_b1  = (const float*)d_in[25];
  const float* tcn_W2  = (const float*)d_in[26];
  const float* tcn_b2  = (const float*)d_in[27];
  const float* out_W   = (const float*)d_in[28];
  const float* out_b   = (const float*)d_in[29];
  float* out = (float*)d_out;
  (void)in_sizes; (void)n_in; (void)out_size; (void)ws_size;

  char* ws = (char*)d_ws;
  size_t off = 0;
  auto alloc = [&](size_t bytes)->void*{
    void* p = (void*)(ws + off); off += (bytes + 255) & ~(size_t)255; return p; };
  float* X       = (float*)alloc((size_t)B_*NT_*L_*4);
  float* adj     = (float*)alloc((size_t)B_*NT_*NT_*4);   // reused as xw after GCN
  float* Xtmp    = (float*)alloc((size_t)B_*NT_*L_*4);
  float* te_in   = (float*)alloc((size_t)B_*T_*GIN_*4);
  float* te_xw   = (float*)alloc((size_t)B_*T_*TE3_*4);
  float* WihT_te = (float*)alloc((size_t)GIN_*TE3_*4);
  float* WihT_tr = (float*)alloc((size_t)L_*TR3_*4);
  float* XtBuf   = (float*)alloc((size_t)T_*B_*L_*4);
  float* hm      = (float*)alloc((size_t)B_*TRH_*4);
  u16*   hb0     = (u16*)alloc((size_t)B_*TRH_*2);
  u16*   hb1     = (u16*)alloc((size_t)B_*TRH_*2);
  unsigned* cnt  = (unsigned*)alloc(256);
  float* nout8   = (float*)alloc((size_t)B_*N_*8*4);
  float* tout8   = (float*)alloc((size_t)B_*N_*8*4);
  float* xw      = adj;   // 46.2MB <= 100MB, adj dead by the time xw is written

  // init persistent-scan state
  hipMemsetAsync(hm, 0, (size_t)B_*TRH_*4, stream);
  hipMemsetAsync(hb0, 0, (size_t)B_*TRH_*2, stream);
  hipMemsetAsync(cnt, 0, 256, stream);

  // weight transposes
  k_transpose<<<dim3(24,6),256,0,stream>>>(te_Wih, WihT_te, TE3_, GIN_);
  k_transpose<<<dim3(2,68),256,0,stream>>>(tr_Wih, WihT_tr, TR3_, L_);
  // SE path
  k_se<<<B_*N_,64,0,stream>>>(x, se_emb, se_W1, se_b1, se_W2, se_b2, X);
  // te path
  k_tein_x<<<dim3(23,6,B_),256,0,stream>>>(x, te_in);
  k_tein_rest<<<(B_*T_*36+255)/256,256,0,stream>>>(mark, te_emb, te_in);
  k_gemm_bias<<<dim3(84,3),256,0,stream>>>(te_in, WihT_te, te_bih, te_xw, B_*T_, TE3_, GIN_);
  k_te_scan<<<B_,192,0,stream>>>(te_xw, te_Whh, te_bhh, X);
  // GCN
  for (int i = 0; i < 2; ++i){
    k_adj<<<dim3(28,28,B_),256,0,stream>>>(X, adj);
    k_gcn<<<dim3(28,B_),256,0,stream>>>(adj, X,    gcn_W + (i*2+0)*4096, gcn_b + (i*2+0)*64, Xtmp);
    k_gcn<<<dim3(28,B_),256,0,stream>>>(adj, Xtmp, gcn_W + (i*2+1)*4096, gcn_b + (i*2+1)*64, X);
  }
  // fr path (last 8 cols only)
  k_fr<<<B_*N_,192,0,stream>>>(X, fr_W1, fr_b1, fr_W2, fr_b2, nout8);
  // tr GRU: input projection for all t, then persistent MFMA scan
  k_xtbuf<<<(T_*B_*L_+255)/256,256,0,stream>>>(X, XtBuf);
  k_gemm_bias<<<dim3(84,34),256,0,stream>>>(XtBuf, WihT_tr, tr_bih, xw, B_*T_, TR3_, L_);
  k_tr_scan<<<TRBLKS,192,0,stream>>>(tr_Whh, tr_bhh, xw, hm, hb0, hb1, tout8, cnt);
  // fused TCN tail
  k_tcn<<<(B_*N_+255)/256,256,0,stream>>>(nout8, tout8, x,
      tcn_W0, tcn_b0, tcn_W1, tcn_b1, tcn_W2, tcn_b2, out_W, out_b, out);
}

// Round 4
// 2560.032 us; speedup vs baseline: 4.3015x; 1.2746x over previous
//
#include <hip/hip_runtime.h>

#define B_   32
#define N_   716
#define T_   168
#define L_   64
#define NT_  884     // N + T
#define NTP  896     // padded NT for bf16 tiles
#define GIN_ 752     // N + SED + TED
#define TE3_ 192     // 3*L
#define TRH_ 716     // tr hidden
#define TR3_ 2148    // 3*TRH
#define WSTR 744     // padded bf16 row stride in LDS
#define HSTR 720     // padded bf16 row stride of global h buffers
#define TRBLKS 90    // 45 k-slices x 2 batch halves

typedef unsigned short u16;
typedef __attribute__((ext_vector_type(8))) short short8;
typedef __attribute__((ext_vector_type(4))) float f32x4;

static __device__ __forceinline__ float eluf(float x){ return x > 0.f ? x : expm1f(x); }
static __device__ __forceinline__ float sigf(float x){ return 1.f/(1.f+expf(-x)); }
static __device__ __forceinline__ u16 f2bf(float f){
  unsigned u = __float_as_uint(f);
  unsigned r = (u + 0x7fffu + ((u >> 16) & 1u)) >> 16;
  return (u16)r;
}
static __device__ __forceinline__ float bf2f(u16 h){
  return __uint_as_float(((unsigned)h) << 16);
}
static __device__ __forceinline__ f32x4 bmfma(short8 a, short8 b, f32x4 c){
  return __builtin_amdgcn_mfma_f32_16x16x32_bf16(a, b, c, 0, 0, 0);
}

// ---------------- generic transpose: out[c][r] = in[r][c] ----------------
__global__ __launch_bounds__(256) void k_transpose(const float* __restrict__ in,
                                                   float* __restrict__ out, int R, int C){
  __shared__ float tile[32][33];
  int c0 = blockIdx.x*32, r0 = blockIdx.y*32;
  int tx = threadIdx.x & 31, ty = threadIdx.x >> 5;
  for (int i = ty; i < 32; i += 8){
    int r = r0 + i, c = c0 + tx;
    if (r < R && c < C) tile[i][tx] = in[(size_t)r*C + c];
  }
  __syncthreads();
  for (int i = ty; i < 32; i += 8){
    int c = c0 + i, r = r0 + tx;
    if (c < C && r < R) out[(size_t)c*R + r] = tile[tx][i];
  }
}

// ---------------- weight conversions ----------------
__global__ __launch_bounds__(256) void k_whhbf(const float* __restrict__ in, u16* __restrict__ out, int n4){
  int i = blockIdx.x*256 + threadIdx.x;
  if (i >= n4) return;
  f32x4 v = *(const f32x4*)(in + (size_t)i*4);
  uint2 p;
  p.x = (unsigned)f2bf(v[0]) | ((unsigned)f2bf(v[1])<<16);
  p.y = (unsigned)f2bf(v[2]) | ((unsigned)f2bf(v[3])<<16);
  *(uint2*)(out + (size_t)i*4) = p;
}
// gcn W -> transposed bf16 hi/lo: WT[g][f] = W[f][g]
__global__ __launch_bounds__(256) void k_wtb(const float* __restrict__ W,
                                             u16* __restrict__ WTh, u16* __restrict__ WTl){
  int l = blockIdx.x;
  for (int e = threadIdx.x; e < 4096; e += 256){
    int g = e >> 6, f = e & 63;
    float v = W[(size_t)l*4096 + f*64 + g];
    u16 hi = f2bf(v);
    WTh[(size_t)l*4096 + e] = hi;
    WTl[(size_t)l*4096 + e] = f2bf(v - bf2f(hi));
  }
}

// ---------------- SE path ----------------
__global__ __launch_bounds__(64) void k_se(const float* __restrict__ x, const float* __restrict__ se_emb,
                 const float* __restrict__ W1, const float* __restrict__ b1,
                 const float* __restrict__ W2, const float* __restrict__ b2,
                 float* __restrict__ X){
  int bn = blockIdx.x; int b = bn / N_, n = bn % N_;
  int tid = threadIdx.x;
  __shared__ float row[200];
  __shared__ float hid[64];
  for (int i = tid; i < 200; i += 64)
    row[i] = (i < T_) ? x[((size_t)b*N_ + n)*T_ + i] : se_emb[n*32 + (i - T_)];
  __syncthreads();
  float acc = b1[tid];
  for (int k = 0; k < 200; ++k) acc = fmaf(row[k], W1[k*64 + tid], acc);
  hid[tid] = eluf(acc);
  __syncthreads();
  float acc2 = b2[tid];
  for (int k = 0; k < 64; ++k) acc2 = fmaf(hid[k], W2[k*64 + tid], acc2);
  X[((size_t)b*NT_ + n)*L_ + tid] = acc2;
}

// ---------------- te_in construction ----------------
__global__ __launch_bounds__(256) void k_tein_x(const float* __restrict__ x, float* __restrict__ te_in){
  __shared__ float tile[32][33];
  int b = blockIdx.z; int n0 = blockIdx.x*32, t0 = blockIdx.y*32;
  int tx = threadIdx.x & 31, ty = threadIdx.x >> 5;
  for (int i = ty; i < 32; i += 8){
    int n = n0 + i, t = t0 + tx;
    if (n < N_ && t < T_) tile[i][tx] = x[((size_t)b*N_ + n)*T_ + t];
  }
  __syncthreads();
  for (int i = ty; i < 32; i += 8){
    int t = t0 + i, n = n0 + tx;
    if (t < T_ && n < N_) te_in[((size_t)b*T_ + t)*GIN_ + n] = tile[tx][i];
  }
}
__global__ __launch_bounds__(256) void k_tein_rest(const float* __restrict__ mark,
                    const float* __restrict__ te_emb, float* __restrict__ te_in){
  int idx = blockIdx.x*256 + threadIdx.x;
  if (idx >= B_*T_*36) return;
  int c = idx % 36; int row = idx / 36; int b = row / T_, t = row % T_;
  float v = (c < 4) ? mark[((size_t)b*T_ + t)*4 + c] : te_emb[t*32 + (c-4)];
  te_in[(size_t)row*GIN_ + N_ + c] = v;
}

// ---------------- generic tiled GEMM C = A@B + bias ----------------
__global__ __launch_bounds__(256) void k_gemm_bias(const float* __restrict__ A, const float* __restrict__ Bm,
                   const float* __restrict__ bias, float* __restrict__ C,
                   int M, int N, int K){
  __shared__ float As[16][65];
  __shared__ float Bs[16][65];
  int m0 = blockIdx.x*64, n0 = blockIdx.y*64;
  int tid = threadIdx.x;
  int tx = tid & 15, ty = tid >> 4;
  float acc[4][4] = {};
  for (int kt = 0; kt < K; kt += 16){
    for (int l = tid; l < 64*16; l += 256){
      int m = l >> 4, kk = l & 15;
      int gm = m0 + m, gk = kt + kk;
      As[kk][m] = (gm < M && gk < K) ? A[(size_t)gm*K + gk] : 0.f;
    }
    for (int l = tid; l < 16*64; l += 256){
      int kk = l >> 6, n = l & 63;
      int gk = kt + kk, gn = n0 + n;
      Bs[kk][n] = (gk < K && gn < N) ? Bm[(size_t)gk*N + gn] : 0.f;
    }
    __syncthreads();
    #pragma unroll 4
    for (int kk = 0; kk < 16; ++kk){
      float a[4], bb[4];
      #pragma unroll
      for (int i = 0; i < 4; ++i) a[i] = As[kk][ty + 16*i];
      #pragma unroll
      for (int j = 0; j < 4; ++j) bb[j] = Bs[kk][tx + 16*j];
      #pragma unroll
      for (int i = 0; i < 4; ++i)
        #pragma unroll
        for (int j = 0; j < 4; ++j) acc[i][j] = fmaf(a[i], bb[j], acc[i][j]);
    }
    __syncthreads();
  }
  for (int i = 0; i < 4; ++i){
    int gm = m0 + ty + 16*i; if (gm >= M) continue;
    for (int j = 0; j < 4; ++j){
      int gn = n0 + tx + 16*j; if (gn >= N) continue;
      C[(size_t)gm*N + gn] = acc[i][j] + bias[gn];
    }
  }
}

// ---------------- te GRU scan ----------------
__global__ __launch_bounds__(192) void k_te_scan(const float* __restrict__ xw, const float* __restrict__ Whh,
                 const float* __restrict__ bhh, float* __restrict__ X){
  int b = blockIdx.x; int tid = threadIdx.x;
  __shared__ float Wsh[TE3_*65];
  __shared__ float hs[64];
  __shared__ float gh[TE3_];
  for (int l = tid; l < TE3_*64; l += 192){ int j = l >> 6, f = l & 63; Wsh[j*65+f] = Whh[l]; }
  if (tid < 64) hs[tid] = 0.f;
  __syncthreads();
  for (int t = 0; t < T_; ++t){
    const float* xr = xw + ((size_t)b*T_ + t)*TE3_;
    float g = bhh[tid];
    #pragma unroll 8
    for (int f = 0; f < 64; ++f) g = fmaf(hs[f], Wsh[tid*65+f], g);
    gh[tid] = g;
    __syncthreads();
    if (tid < 64){
      float r = sigf(xr[tid] + gh[tid]);
      float z = sigf(xr[64+tid] + gh[64+tid]);
      float n = tanhf(xr[128+tid] + r*gh[128+tid]);
      float hn = (1.f - z)*n + z*hs[tid];
      hs[tid] = hn;
      X[((size_t)b*NT_ + N_ + t)*L_ + tid] = hn;
    }
    __syncthreads();
  }
}

// ---------------- X -> bf16 hi/lo (row-major + transposed, pads zeroed) ----------------
__global__ __launch_bounds__(256) void k_xbf(const float* __restrict__ X,
                 u16* __restrict__ Xbh, u16* __restrict__ Xbl,
                 u16* __restrict__ XTh, u16* __restrict__ XTl){
  __shared__ u16 th[32][33], tl[32][33];
  int b = blockIdx.z, i0 = blockIdx.x*32, f0 = blockIdx.y*32;
  int tx = threadIdx.x & 31, ty = threadIdx.x >> 5;
  for (int rr = ty; rr < 32; rr += 8){
    int i = i0 + rr, f = f0 + tx;
    float v = (i < NT_) ? X[((size_t)b*NT_ + i)*L_ + f] : 0.f;
    u16 hi = f2bf(v);
    u16 lo = f2bf(v - bf2f(hi));
    th[rr][tx] = hi; tl[rr][tx] = lo;
    Xbh[((size_t)b*NTP + i)*L_ + f] = hi;
    Xbl[((size_t)b*NTP + i)*L_ + f] = lo;
  }
  __syncthreads();
  for (int rr = ty; rr < 32; rr += 8){
    XTh[((size_t)b*L_ + f0 + rr)*NTP + i0 + tx] = th[tx][rr];
    XTl[((size_t)b*L_ + f0 + rr)*NTP + i0 + tx] = tl[tx][rr];
  }
}

// ---------------- adjacency (MFMA bf16 hi/lo): adj = tanh(relu(X X^T)+I) ----------------
__global__ __launch_bounds__(256) void k_adjb(const u16* __restrict__ Xbh, const u16* __restrict__ Xbl,
                                              u16* __restrict__ adjh, u16* __restrict__ adjl){
  int b = blockIdx.z, i0 = blockIdx.x*64, j0 = blockIdx.y*64;
  int tid = threadIdx.x, wv = tid >> 6, lane = tid & 63;
  const u16* Ah = Xbh + ((size_t)b*NTP + i0 + 16*wv + (lane & 15))*L_ + (lane >> 4)*8;
  const u16* Al = Xbl + ((size_t)b*NTP + i0 + 16*wv + (lane & 15))*L_ + (lane >> 4)*8;
  const u16* Bh = Xbh + ((size_t)b*NTP + j0 + (lane & 15))*L_ + (lane >> 4)*8;
  const u16* Bl = Xbl + ((size_t)b*NTP + j0 + (lane & 15))*L_ + (lane >> 4)*8;
  f32x4 chh[4], chl[4], clh[4];
  #pragma unroll
  for (int q = 0; q < 4; ++q){ chh[q] = (f32x4){0,0,0,0}; chl[q] = (f32x4){0,0,0,0}; clh[q] = (f32x4){0,0,0,0}; }
  #pragma unroll
  for (int kt = 0; kt < 2; ++kt){
    short8 ah = *(const short8*)(Ah + kt*32);
    short8 al = *(const short8*)(Al + kt*32);
    #pragma unroll
    for (int q = 0; q < 4; ++q){
      short8 bh = *(const short8*)(Bh + q*16*L_ + kt*32);
      short8 bl = *(const short8*)(Bl + q*16*L_ + kt*32);
      chh[q] = bmfma(ah, bh, chh[q]);
      chl[q] = bmfma(ah, bl, chl[q]);
      clh[q] = bmfma(al, bh, clh[q]);
    }
  }
  int ib = i0 + 16*wv + (lane >> 4)*4;
  int jb = j0 + (lane & 15);
  #pragma unroll
  for (int q = 0; q < 4; ++q){
    int j = jb + q*16;
    #pragma unroll
    for (int r = 0; r < 4; ++r){
      int i = ib + r;
      size_t idx = ((size_t)b*NTP + i)*NTP + j;
      if (i < NT_ && j < NT_){
        float v = tanhf(fmaxf(chh[q][r] + chl[q][r] + clh[q][r], 0.f) + (i == j ? 1.f : 0.f));
        u16 hi = f2bf(v);
        adjh[idx] = hi;
        adjl[idx] = f2bf(v - bf2f(hi));
      } else {
        adjh[idx] = 0; adjl[idx] = 0;
      }
    }
  }
}

// ---------------- fused GCN layer (MFMA bf16 hi/lo): Y = elu((adj@h)@W + b) ----------------
__global__ __launch_bounds__(256) void k_gcnm(const u16* __restrict__ adjh, const u16* __restrict__ adjl,
                 const u16* __restrict__ hTh, const u16* __restrict__ hTl,
                 const u16* __restrict__ WTh, const u16* __restrict__ WTl,
                 const float* __restrict__ bias,
                 float* __restrict__ Y, u16* __restrict__ YTh, u16* __restrict__ YTl){
  __shared__ u16 Tlh[64*72], Tll[64*72];
  int b = blockIdx.y, i0 = blockIdx.x*64;
  int tid = threadIdx.x, wv = tid >> 6, lane = tid & 63;
  // stage 1: T[i][f] = sum_j adj[i][j] h[j][f]
  const u16* Ah = adjh + ((size_t)b*NTP + i0 + 16*wv + (lane & 15))*NTP + (lane >> 4)*8;
  const u16* Al = adjl + ((size_t)b*NTP + i0 + 16*wv + (lane & 15))*NTP + (lane >> 4)*8;
  const u16* Bh = hTh + ((size_t)b*L_ + (lane & 15))*NTP + (lane >> 4)*8;
  const u16* Bl = hTl + ((size_t)b*L_ + (lane & 15))*NTP + (lane >> 4)*8;
  f32x4 thh[4], thl[4], tlh[4];
  #pragma unroll
  for (int q = 0; q < 4; ++q){ thh[q] = (f32x4){0,0,0,0}; thl[q] = (f32x4){0,0,0,0}; tlh[q] = (f32x4){0,0,0,0}; }
  #pragma unroll 2
  for (int kt = 0; kt < 28; ++kt){
    short8 ah = *(const short8*)(Ah + kt*32);
    short8 al = *(const short8*)(Al + kt*32);
    #pragma unroll
    for (int q = 0; q < 4; ++q){
      short8 bh = *(const short8*)(Bh + q*16*NTP + kt*32);
      short8 bl = *(const short8*)(Bl + q*16*NTP + kt*32);
      thh[q] = bmfma(ah, bh, thh[q]);
      thl[q] = bmfma(ah, bl, thl[q]);
      tlh[q] = bmfma(al, bh, tlh[q]);
    }
  }
  // T -> LDS bf16 hi/lo (rows m, cols f)
  {
    int mrow = 16*wv + (lane >> 4)*4;
    #pragma unroll
    for (int q = 0; q < 4; ++q)
      #pragma unroll
      for (int r = 0; r < 4; ++r){
        float v = thh[q][r] + thl[q][r] + tlh[q][r];
        u16 hi = f2bf(v);
        Tlh[(mrow + r)*72 + q*16 + (lane & 15)] = hi;
        Tll[(mrow + r)*72 + q*16 + (lane & 15)] = f2bf(v - bf2f(hi));
      }
  }
  __syncthreads();
  // stage 2: D2[i][g] = sum_f T[i][f] WT[g][f]
  const u16* A2h = Tlh + (16*wv + (lane & 15))*72 + (lane >> 4)*8;
  const u16* A2l = Tll + (16*wv + (lane & 15))*72 + (lane >> 4)*8;
  const u16* B2h = WTh + (lane & 15)*L_ + (lane >> 4)*8;
  const u16* B2l = WTl + (lane & 15)*L_ + (lane >> 4)*8;
  f32x4 ohh[4], ohl[4], olh[4];
  #pragma unroll
  for (int q = 0; q < 4; ++q){ ohh[q] = (f32x4){0,0,0,0}; ohl[q] = (f32x4){0,0,0,0}; olh[q] = (f32x4){0,0,0,0}; }
  #pragma unroll
  for (int kt = 0; kt < 2; ++kt){
    short8 a2h = *(const short8*)(A2h + kt*32);
    short8 a2l = *(const short8*)(A2l + kt*32);
    #pragma unroll
    for (int q = 0; q < 4; ++q){
      short8 b2h = *(const short8*)(B2h + q*16*L_ + kt*32);
      short8 b2l = *(const short8*)(B2l + q*16*L_ + kt*32);
      ohh[q] = bmfma(a2h, b2h, ohh[q]);
      ohl[q] = bmfma(a2h, b2l, ohl[q]);
      olh[q] = bmfma(a2l, b2h, olh[q]);
    }
  }
  __syncthreads();   // stage-2 LDS reads done; Tl* may be overwritten
  {
    int mrow = 16*wv + (lane >> 4)*4;
    #pragma unroll
    for (int q = 0; q < 4; ++q){
      int g = q*16 + (lane & 15);
      float bv = bias[g];
      #pragma unroll
      for (int r = 0; r < 4; ++r){
        int i = i0 + mrow + r;
        float v = eluf(ohh[q][r] + ohl[q][r] + olh[q][r] + bv);
        if (i < NT_ && Y) Y[((size_t)b*NT_ + i)*L_ + g] = v;
        u16 hi = 0, lo = 0;
        if (i < NT_){ hi = f2bf(v); lo = f2bf(v - bf2f(hi)); }
        Tlh[g*72 + mrow + r] = hi;
        Tll[g*72 + mrow + r] = lo;
      }
    }
  }
  __syncthreads();
  // coalesced YT write: 64 g-rows x 64 cols
  {
    int g = tid >> 2, c = tid & 3;
    uint4* dh = (uint4*)(YTh + ((size_t)b*L_ + g)*NTP + i0 + c*16);
    uint4* dl = (uint4*)(YTl + ((size_t)b*L_ + g)*NTP + i0 + c*16);
    const uint4* sh = (const uint4*)(Tlh + g*72 + c*16);
    const uint4* sl = (const uint4*)(Tll + g*72 + c*16);
    dh[0] = sh[0]; dh[1] = sh[1];
    dl[0] = sl[0]; dl[1] = sl[1];
  }
}

// ---------------- fr path: only output cols 160..167 needed ----------------
__global__ __launch_bounds__(192) void k_fr(const float* __restrict__ X, const float* __restrict__ W1,
                const float* __restrict__ b1, const float* __restrict__ W2,
                const float* __restrict__ b2, float* __restrict__ nout8){
  int bn = blockIdx.x; int b = bn / N_, n = bn % N_;
  int tid = threadIdx.x;
  __shared__ float xs[64];
  __shared__ float t1[T_];
  __shared__ float part[24*8];
  if (tid < 64) xs[tid] = X[((size_t)b*NT_+n)*L_+tid];
  __syncthreads();
  if (tid < T_){
    float a = b1[tid];
    #pragma unroll 8
    for (int ff = 0; ff < 64; ++ff) a = fmaf(xs[ff], W1[ff*T_+tid], a);
    t1[tid] = eluf(a);
  }
  __syncthreads();
  int c = tid & 7, p = tid >> 3;
  float s = 0.f;
  for (int ff = p; ff < T_; ff += 24) s = fmaf(t1[ff], W2[ff*T_ + 160 + c], s);
  part[p*8 + c] = s;
  __syncthreads();
  if (tid < 8){
    float a = b2[160 + tid];
    #pragma unroll
    for (int q = 0; q < 24; ++q) a += part[q*8 + tid];
    nout8[((size_t)bn)*8 + tid] = a;
  }
}

// ---------------- gather Xt into (T, B, 64) layout ----------------
__global__ __launch_bounds__(256) void k_xtbuf(const float* __restrict__ X, float* __restrict__ XtBuf){
  int idx = blockIdx.x*256 + threadIdx.x;
  if (idx >= T_*B_*L_) return;
  int f = idx & 63; int tb = idx >> 6; int bb = tb & 31; int t = tb >> 5;
  XtBuf[idx] = X[((size_t)bb*NT_ + N_ + t)*L_ + f];
}

// ---------------- persistent MFMA tr-GRU scan ----------------
__global__ __launch_bounds__(192) void k_tr_scan(
    const u16* __restrict__ WhhB,  // (2148, 716) bf16
    const float* __restrict__ bhh,
    const float* __restrict__ xw,  // (5376, 2148) incl. bih
    u16* __restrict__ hb0, u16* __restrict__ hb1,  // (32, 720) bf16
    float* __restrict__ tout8,
    int* __restrict__ flags, int* __restrict__ go){
  __shared__ u16 w_lds[48*WSTR];
  __shared__ u16 h_lds[16*WSTR];
  __shared__ float g_lds[2*256];
  __shared__ float xw_lds[16*48];
  const int tid = threadIdx.x;
  const int wv = tid >> 6, lane = tid & 63;
  const int cb = blockIdx.x >> 1, hhalf = blockIdx.x & 1;
  const int k0 = cb*16, b0 = hhalf*16;

  // xw prefetch for step 0
  {
    int row = tid / 12, c = tid % 12;
    int g = c >> 2, koff = (c & 3)*4;
    *(f32x4*)(xw_lds + row*48 + g*16 + koff) =
      *(const f32x4*)(xw + (size_t)(b0 + row)*TR3_ + g*TRH_ + k0 + koff);
  }
  // zero h_lds pad cols [720..744) once (staging only covers 0..719)
  for (int o = tid; o < 16*24; o += 192){
    int n = o / 24, c = o - n*24;
    h_lds[n*WSTR + 720 + c] = 0;
  }
  // stage weights bf16 -> LDS; rows r = gate*16+m, zero-pad cols >=716
  for (int r = 0; r < 48; ++r){
    int g = r >> 4, m = r & 15, k = k0 + m;
    bool kv = (k < TRH_);
    const uint2* src = (const uint2*)(WhhB + (size_t)(g*TRH_ + (kv ? k : 0))*TRH_);
    uint2* dst = (uint2*)(w_lds + r*WSTR);
    uint2 zz; zz.x = 0; zz.y = 0;
    for (int o = tid; o < 186; o += 192)
      dst[o] = (kv && o < 179) ? src[o] : zz;
  }
  const u16* arow = w_lds + (size_t)(wv*16 + (lane & 15))*WSTR + (lane >> 4)*8;
  const u16* brow = h_lds + (size_t)(lane & 15)*WSTR + (lane >> 4)*8;

  const int mb = (lane >> 4)*4;
  const int kx = k0 + mb;
  const bool kval = (kx < TRH_);
  const int bx = b0 + (lane & 15);
  f32x4 hp = {0.f, 0.f, 0.f, 0.f};
  f32x4 br4 = {0,0,0,0}, bz4 = {0,0,0,0}, bn4 = {0,0,0,0};
  if (wv == 0){
    int kc = kval ? kx : 0;
    br4 = *(const f32x4*)(bhh + kc);
    bz4 = *(const f32x4*)(bhh + TRH_ + kc);
    bn4 = *(const f32x4*)(bhh + 2*TRH_ + kc);
  }
  __syncthreads();

  for (int t = 0; t < T_; ++t){
    const u16* hcur = (t & 1) ? hb1 : hb0;
    u16* hnxt = (t & 1) ? hb0 : hb1;
    // stage h: 16 rows x 90 uint4 (16B)
    for (int o = tid; o < 16*90; o += 192){
      int n = o / 90, c = o - n*90;
      *(uint4*)(h_lds + n*WSTR + c*8) = *(const uint4*)(hcur + (size_t)(b0 + n)*HSTR + c*8);
    }
    __syncthreads();
    // MFMA over 23 k-tiles, 4 independent chains
    f32x4 a0={0,0,0,0}, a1={0,0,0,0}, a2={0,0,0,0}, a3={0,0,0,0};
    for (int kt = 0; kt < 20; kt += 4){
      a0 = bmfma(*(const short8*)(arow + kt*32),     *(const short8*)(brow + kt*32),     a0);
      a1 = bmfma(*(const short8*)(arow + (kt+1)*32), *(const short8*)(brow + (kt+1)*32), a1);
      a2 = bmfma(*(const short8*)(arow + (kt+2)*32), *(const short8*)(brow + (kt+2)*32), a2);
      a3 = bmfma(*(const short8*)(arow + (kt+3)*32), *(const short8*)(brow + (kt+3)*32), a3);
    }
    a0 = bmfma(*(const short8*)(arow + 20*32), *(const short8*)(brow + 20*32), a0);
    a1 = bmfma(*(const short8*)(arow + 21*32), *(const short8*)(brow + 21*32), a1);
    a2 = bmfma(*(const short8*)(arow + 22*32), *(const short8*)(brow + 22*32), a2);
    f32x4 acc = (a0 + a1) + (a2 + a3);
    if (wv){
      #pragma unroll
      for (int r = 0; r < 4; ++r) g_lds[(wv-1)*256 + lane*4 + r] = acc[r];
    }
    __syncthreads();
    if (wv == 0 && kval){
      const float* xb = xw_lds + (lane & 15)*48;
      float hnew[4];
      #pragma unroll
      for (int r = 0; r < 4; ++r){
        float rg = sigf(xb[mb + r] + acc[r] + br4[r]);
        float zg = sigf(xb[16 + mb + r] + g_lds[lane*4 + r] + bz4[r]);
        float ng = tanhf(xb[32 + mb + r] + rg*(g_lds[256 + lane*4 + r] + bn4[r]));
        hnew[r] = (1.f - zg)*ng + zg*hp[r];
        hp[r] = hnew[r];
      }
      uint2 pk;
      pk.x = (unsigned)f2bf(hnew[0]) | ((unsigned)f2bf(hnew[1]) << 16);
      pk.y = (unsigned)f2bf(hnew[2]) | ((unsigned)f2bf(hnew[3]) << 16);
      *(uint2*)(hnxt + (size_t)bx*HSTR + kx) = pk;
      if (t >= 160){
        #pragma unroll
        for (int r = 0; r < 4; ++r)
          tout8[(size_t)(bx*TRH_ + kx + r)*8 + (t - 160)] = hnew[r];
      }
    }
    __syncthreads();
    // prefetch xw for t+1 (overlaps the barrier)
    if (t + 1 < T_){
      int row = tid / 12, c = tid % 12;
      int g = c >> 2, koff = (c & 3)*4;
      *(f32x4*)(xw_lds + row*48 + g*16 + koff) =
        *(const f32x4*)(xw + (size_t)((t+1)*32 + b0 + row)*TR3_ + g*TRH_ + k0 + koff);
    }
    // grid barrier: per-block flag lines + block-0 go broadcast
    if (tid == 0)
      __hip_atomic_store(&flags[blockIdx.x*16], t + 1, __ATOMIC_RELEASE, __HIP_MEMORY_SCOPE_AGENT);
    if (blockIdx.x == 0){
      if (tid < TRBLKS){
        while (__hip_atomic_load(&flags[tid*16], __ATOMIC_RELAXED, __HIP_MEMORY_SCOPE_AGENT) < t + 1){}
      }
      __builtin_amdgcn_fence(__ATOMIC_ACQUIRE, "agent");
      __syncthreads();
      if (tid == 0)
        __hip_atomic_store(go, t + 1, __ATOMIC_RELEASE, __HIP_MEMORY_SCOPE_AGENT);
    }
    if (tid == 0){
      while (__hip_atomic_load(go, __ATOMIC_ACQUIRE, __HIP_MEMORY_SCOPE_AGENT) < t + 1){
        __builtin_amdgcn_s_sleep(1);
      }
    }
    __syncthreads();
  }
}

// ---------------- fused TCN tail ----------------
__global__ __launch_bounds__(256) void k_tcn(const float* __restrict__ nout8, const float* __restrict__ tout8,
                 const float* __restrict__ x,
                 const float* __restrict__ W0, const float* __restrict__ b0,
                 const float* __restrict__ W1, const float* __restrict__ b1,
                 const float* __restrict__ W2, const float* __restrict__ b2,
                 const float* __restrict__ oW, const float* __restrict__ ob,
                 float* __restrict__ out){
  __shared__ float w0s[96], b0s[16], w1s[512], b1s[16], w2s[512], b2s[16], ows[16], obs;
  int tid = threadIdx.x;
  for (int l = tid; l < 96; l += 256) w0s[l] = W0[l];
  for (int l = tid; l < 512; l += 256){ w1s[l] = W1[l]; w2s[l] = W2[l]; }
  if (tid < 16){ b0s[tid]=b0[tid]; b1s[tid]=b1[tid]; b2s[tid]=b2[tid]; ows[tid]=oW[tid]; }
  if (tid == 0) obs = ob[0];
  __syncthreads();
  int idx = blockIdx.x*256 + tid;
  if (idx >= B_*N_) return;
  int b = idx / N_, n = idx % N_;
  float s0[8], s1[8], s2[8];
  #pragma unroll
  for (int i = 0; i < 8; ++i){
    s0[i] = nout8[(size_t)idx*8 + i];
    s1[i] = tout8[(size_t)idx*8 + i];
    s2[i] = x[((size_t)b*N_ + n)*T_ + 160 + i];
  }
  float h1[16][4];
  #pragma unroll
  for (int c = 0; c < 16; ++c)
    #pragma unroll
    for (int q = 0; q < 4; ++q){
      int tt = 2*q + 1;
      float v = b0s[c]
        + w0s[c*6+0]*s0[tt-1] + w0s[c*6+1]*s0[tt]
        + w0s[c*6+2]*s1[tt-1] + w0s[c*6+3]*s1[tt]
        + w0s[c*6+4]*s2[tt-1] + w0s[c*6+5]*s2[tt];
      h1[c][q] = eluf(v);
    }
  float h2[16][2];
  #pragma unroll
  for (int c = 0; c < 16; ++c){
    float v3 = b1s[c], v7 = b1s[c];
    #pragma unroll
    for (int i2 = 0; i2 < 16; ++i2){
      v3 += w1s[c*32+i2*2]*h1[i2][0] + w1s[c*32+i2*2+1]*h1[i2][1];
      v7 += w1s[c*32+i2*2]*h1[i2][2] + w1s[c*32+i2*2+1]*h1[i2][3];
    }
    h2[c][0] = eluf(v3); h2[c][1] = eluf(v7);
  }
  float o = obs;
  #pragma unroll
  for (int c = 0; c < 16; ++c){
    float v = b2s[c];
    #pragma unroll
    for (int i2 = 0; i2 < 16; ++i2)
      v += w2s[c*32+i2*2]*h2[i2][0] + w2s[c*32+i2*2+1]*h2[i2][1];
    o += ows[c]*eluf(v);
  }
  out[idx] = o;
}

extern "C" void kernel_launch(void* const* d_in, const int* in_sizes, int n_in,
                              void* d_out, int out_size, void* d_ws, size_t ws_size,
                              hipStream_t stream){
  const float* x       = (const float*)d_in[0];
  const float* mark    = (const float*)d_in[1];
  const float* se_emb  = (const float*)d_in[2];
  const float* se_W1   = (const float*)d_in[3];
  const float* se_b1   = (const float*)d_in[4];
  const float* se_W2   = (const float*)d_in[5];
  const float* se_b2   = (const float*)d_in[6];
  const float* te_emb  = (const float*)d_in[7];
  const float* te_Wih  = (const float*)d_in[8];
  const float* te_Whh  = (const float*)d_in[9];
  const float* te_bih  = (const float*)d_in[10];
  const float* te_bhh  = (const float*)d_in[11];
  const float* gcn_W   = (const float*)d_in[12];
  const float* gcn_b   = (const float*)d_in[13];
  const float* fr_W1   = (const float*)d_in[14];
  const float* fr_b1   = (const float*)d_in[15];
  const float* fr_W2   = (const float*)d_in[16];
  const float* fr_b2   = (const float*)d_in[17];
  const float* tr_Wih  = (const float*)d_in[18];
  const float* tr_Whh  = (const float*)d_in[19];
  const float* tr_bih  = (const float*)d_in[20];
  const float* tr_bhh  = (const float*)d_in[21];
  const float* tcn_W0  = (const float*)d_in[22];
  const float* tcn_b0  = (const float*)d_in[23];
  const float* tcn_W1  = (const float*)d_in[24];
  const float* tcn_b1  = (const float*)d_in[25];
  const float* tcn_W2  = (const float*)d_in[26];
  const float* tcn_b2  = (const float*)d_in[27];
  const float* out_W   = (const float*)d_in[28];
  const float* out_b   = (const float*)d_in[29];
  float* out = (float*)d_out;
  (void)in_sizes; (void)n_in; (void)out_size; (void)ws_size;

  char* ws = (char*)d_ws;
  size_t off = 0;
  auto alloc = [&](size_t bytes)->void*{
    void* p = (void*)(ws + off); off += (bytes + 255) & ~(size_t)255; return p; };
  float* X       = (float*)alloc((size_t)B_*NT_*L_*4);
  u16*   adjh    = (u16*)  alloc((size_t)B_*NTP*NTP*2);   // 51.4MB
  u16*   adjl    = (u16*)  alloc((size_t)B_*NTP*NTP*2);   // 51.4MB
  float* WihT_tr = (float*)alloc((size_t)L_*TR3_*4);
  float* XtBuf   = (float*)alloc((size_t)T_*B_*L_*4);
  u16*   WhhB    = (u16*)  alloc((size_t)TR3_*TRH_*2);
  u16*   Xbh     = (u16*)  alloc((size_t)B_*NTP*L_*2);
  u16*   Xbl     = (u16*)  alloc((size_t)B_*NTP*L_*2);
  u16*   hTah    = (u16*)  alloc((size_t)B_*L_*NTP*2);
  u16*   hTal    = (u16*)  alloc((size_t)B_*L_*NTP*2);
  u16*   hTbh    = (u16*)  alloc((size_t)B_*L_*NTP*2);
  u16*   hTbl    = (u16*)  alloc((size_t)B_*L_*NTP*2);
  u16*   WTh     = (u16*)  alloc((size_t)4*4096*2);
  u16*   WTl     = (u16*)  alloc((size_t)4*4096*2);
  u16*   hb0     = (u16*)  alloc((size_t)B_*HSTR*2);
  u16*   hb1     = (u16*)  alloc((size_t)B_*HSTR*2);
  int*   flags   = (int*)  alloc(8192);
  int*   go      = (int*)  alloc(256);
  float* nout8   = (float*)alloc((size_t)B_*N_*8*4);
  float* tout8   = (float*)alloc((size_t)B_*N_*8*4);
  // aliases: te buffers live only BEFORE the GCN (inside adjh);
  //          xw is written only AFTER the GCN (inside adjl)
  float* te_in   = (float*)adjh;                            // 16,171,008 B
  float* te_xw   = (float*)((char*)adjh + 16171008);        //  4,128,768 B
  float* WihT_te = (float*)((char*)adjh + 20299776);        //    577,536 B
  float* xw      = (float*)adjl;                            // 46,190,592 B

  hipMemsetAsync(hb0, 0, (size_t)B_*HSTR*2, stream);
  hipMemsetAsync(hb1, 0, (size_t)B_*HSTR*2, stream);
  hipMemsetAsync(flags, 0, 8192, stream);
  hipMemsetAsync(go, 0, 256, stream);

  // weight prep
  k_whhbf<<<(TR3_*TRH_/4 + 255)/256, 256, 0, stream>>>(tr_Whh, WhhB, TR3_*TRH_/4);
  k_wtb<<<4, 256, 0, stream>>>(gcn_W, WTh, WTl);
  k_transpose<<<dim3(24,6),256,0,stream>>>(te_Wih, WihT_te, TE3_, GIN_);
  k_transpose<<<dim3(2,68),256,0,stream>>>(tr_Wih, WihT_tr, TR3_, L_);
  // SE path
  k_se<<<B_*N_,64,0,stream>>>(x, se_emb, se_W1, se_b1, se_W2, se_b2, X);
  // te path
  k_tein_x<<<dim3(23,6,B_),256,0,stream>>>(x, te_in);
  k_tein_rest<<<(B_*T_*36+255)/256,256,0,stream>>>(mark, te_emb, te_in);
  k_gemm_bias<<<dim3(84,3),256,0,stream>>>(te_in, WihT_te, te_bih, te_xw, B_*T_, TE3_, GIN_);
  k_te_scan<<<B_,192,0,stream>>>(te_xw, te_Whh, te_bhh, X);
  // GCN (MFMA bf16 hi/lo)
  for (int i = 0; i < 2; ++i){
    k_xbf<<<dim3(28,2,B_),256,0,stream>>>(X, Xbh, Xbl, hTah, hTal);
    k_adjb<<<dim3(14,14,B_),256,0,stream>>>(Xbh, Xbl, adjh, adjl);
    k_gcnm<<<dim3(14,B_),256,0,stream>>>(adjh, adjl, hTah, hTal,
        WTh + (i*2+0)*4096, WTl + (i*2+0)*4096, gcn_b + (i*2+0)*64, nullptr, hTbh, hTbl);
    k_gcnm<<<dim3(14,B_),256,0,stream>>>(adjh, adjl, hTbh, hTbl,
        WTh + (i*2+1)*4096, WTl + (i*2+1)*4096, gcn_b + (i*2+1)*64, X, hTah, hTal);
  }
  // fr path
  k_fr<<<B_*N_,192,0,stream>>>(X, fr_W1, fr_b1, fr_W2, fr_b2, nout8);
  // tr GRU: input projection, then persistent MFMA scan
  k_xtbuf<<<(T_*B_*L_+255)/256,256,0,stream>>>(X, XtBuf);
  k_gemm_bias<<<dim3(84,34),256,0,stream>>>(XtBuf, WihT_tr, tr_bih, xw, B_*T_, TR3_, L_);
  k_tr_scan<<<TRBLKS,192,0,stream>>>(WhhB, tr_bhh, xw, hb0, hb1, tout8, flags, go);
  // fused TCN tail
  k_tcn<<<(B_*N_+255)/256,256,0,stream>>>(nout8, tout8, x,
      tcn_W0, tcn_b0, tcn_W1, tcn_b1, tcn_W2, tcn_b2, out_W, out_b, out);
}

// Round 5
// 2198.564 us; speedup vs baseline: 5.0087x; 1.1644x over previous
//
#include <hip/hip_runtime.h>

#define B_   32
#define N_   716
#define T_   168
#define L_   64
#define NT_  884     // N + T
#define NTP  896     // padded NT for bf16 tiles
#define GIN_ 752     // N + SED + TED
#define TE3_ 192     // 3*L
#define TRH_ 716     // tr hidden
#define TR3_ 2148    // 3*TRH
#define WSTR 744     // padded bf16 row stride in LDS
#define HSTR 720     // padded bf16 row stride of global h buffers
#define TRBLKS 90    // 45 k-slices x 2 batch halves

typedef unsigned short u16;
typedef unsigned long long u64;
typedef __attribute__((ext_vector_type(8))) short short8;
typedef __attribute__((ext_vector_type(4))) float f32x4;

static __device__ __forceinline__ float eluf(float x){ return x > 0.f ? x : expm1f(x); }
static __device__ __forceinline__ float sigf(float x){ return 1.f/(1.f+expf(-x)); }
static __device__ __forceinline__ u16 f2bf(float f){
  unsigned u = __float_as_uint(f);
  unsigned r = (u + 0x7fffu + ((u >> 16) & 1u)) >> 16;
  return (u16)r;
}
static __device__ __forceinline__ float bf2f(u16 h){
  return __uint_as_float(((unsigned)h) << 16);
}
static __device__ __forceinline__ f32x4 bmfma(short8 a, short8 b, f32x4 c){
  return __builtin_amdgcn_mfma_f32_16x16x32_bf16(a, b, c, 0, 0, 0);
}

// ---------------- generic transpose: out[c][r] = in[r][c] ----------------
__global__ __launch_bounds__(256) void k_transpose(const float* __restrict__ in,
                                                   float* __restrict__ out, int R, int C){
  __shared__ float tile[32][33];
  int c0 = blockIdx.x*32, r0 = blockIdx.y*32;
  int tx = threadIdx.x & 31, ty = threadIdx.x >> 5;
  for (int i = ty; i < 32; i += 8){
    int r = r0 + i, c = c0 + tx;
    if (r < R && c < C) tile[i][tx] = in[(size_t)r*C + c];
  }
  __syncthreads();
  for (int i = ty; i < 32; i += 8){
    int c = c0 + i, r = r0 + tx;
    if (c < C && r < R) out[(size_t)c*R + r] = tile[tx][i];
  }
}

// ---------------- weight conversions ----------------
__global__ __launch_bounds__(256) void k_whhbf(const float* __restrict__ in, u16* __restrict__ out, int n4){
  int i = blockIdx.x*256 + threadIdx.x;
  if (i >= n4) return;
  f32x4 v = *(const f32x4*)(in + (size_t)i*4);
  uint2 p;
  p.x = (unsigned)f2bf(v[0]) | ((unsigned)f2bf(v[1])<<16);
  p.y = (unsigned)f2bf(v[2]) | ((unsigned)f2bf(v[3])<<16);
  *(uint2*)(out + (size_t)i*4) = p;
}
// gcn W -> transposed bf16 hi/lo: WT[g][f] = W[f][g]
__global__ __launch_bounds__(256) void k_wtb(const float* __restrict__ W,
                                             u16* __restrict__ WTh, u16* __restrict__ WTl){
  int l = blockIdx.x;
  for (int e = threadIdx.x; e < 4096; e += 256){
    int g = e >> 6, f = e & 63;
    float v = W[(size_t)l*4096 + f*64 + g];
    u16 hi = f2bf(v);
    WTh[(size_t)l*4096 + e] = hi;
    WTl[(size_t)l*4096 + e] = f2bf(v - bf2f(hi));
  }
}

// ---------------- SE path ----------------
__global__ __launch_bounds__(64) void k_se(const float* __restrict__ x, const float* __restrict__ se_emb,
                 const float* __restrict__ W1, const float* __restrict__ b1,
                 const float* __restrict__ W2, const float* __restrict__ b2,
                 float* __restrict__ X){
  int bn = blockIdx.x; int b = bn / N_, n = bn % N_;
  int tid = threadIdx.x;
  __shared__ float row[200];
  __shared__ float hid[64];
  for (int i = tid; i < 200; i += 64)
    row[i] = (i < T_) ? x[((size_t)b*N_ + n)*T_ + i] : se_emb[n*32 + (i - T_)];
  __syncthreads();
  float acc = b1[tid];
  for (int k = 0; k < 200; ++k) acc = fmaf(row[k], W1[k*64 + tid], acc);
  hid[tid] = eluf(acc);
  __syncthreads();
  float acc2 = b2[tid];
  for (int k = 0; k < 64; ++k) acc2 = fmaf(hid[k], W2[k*64 + tid], acc2);
  X[((size_t)b*NT_ + n)*L_ + tid] = acc2;
}

// ---------------- te_in construction ----------------
__global__ __launch_bounds__(256) void k_tein_x(const float* __restrict__ x, float* __restrict__ te_in){
  __shared__ float tile[32][33];
  int b = blockIdx.z; int n0 = blockIdx.x*32, t0 = blockIdx.y*32;
  int tx = threadIdx.x & 31, ty = threadIdx.x >> 5;
  for (int i = ty; i < 32; i += 8){
    int n = n0 + i, t = t0 + tx;
    if (n < N_ && t < T_) tile[i][tx] = x[((size_t)b*N_ + n)*T_ + t];
  }
  __syncthreads();
  for (int i = ty; i < 32; i += 8){
    int t = t0 + i, n = n0 + tx;
    if (t < T_ && n < N_) te_in[((size_t)b*T_ + t)*GIN_ + n] = tile[tx][i];
  }
}
__global__ __launch_bounds__(256) void k_tein_rest(const float* __restrict__ mark,
                    const float* __restrict__ te_emb, float* __restrict__ te_in){
  int idx = blockIdx.x*256 + threadIdx.x;
  if (idx >= B_*T_*36) return;
  int c = idx % 36; int row = idx / 36; int b = row / T_, t = row % T_;
  float v = (c < 4) ? mark[((size_t)b*T_ + t)*4 + c] : te_emb[t*32 + (c-4)];
  te_in[(size_t)row*GIN_ + N_ + c] = v;
}

// ---------------- generic tiled GEMM C = A@B + bias ----------------
__global__ __launch_bounds__(256) void k_gemm_bias(const float* __restrict__ A, const float* __restrict__ Bm,
                   const float* __restrict__ bias, float* __restrict__ C,
                   int M, int N, int K){
  __shared__ float As[16][65];
  __shared__ float Bs[16][65];
  int m0 = blockIdx.x*64, n0 = blockIdx.y*64;
  int tid = threadIdx.x;
  int tx = tid & 15, ty = tid >> 4;
  float acc[4][4] = {};
  for (int kt = 0; kt < K; kt += 16){
    for (int l = tid; l < 64*16; l += 256){
      int m = l >> 4, kk = l & 15;
      int gm = m0 + m, gk = kt + kk;
      As[kk][m] = (gm < M && gk < K) ? A[(size_t)gm*K + gk] : 0.f;
    }
    for (int l = tid; l < 16*64; l += 256){
      int kk = l >> 6, n = l & 63;
      int gk = kt + kk, gn = n0 + n;
      Bs[kk][n] = (gk < K && gn < N) ? Bm[(size_t)gk*N + gn] : 0.f;
    }
    __syncthreads();
    #pragma unroll 4
    for (int kk = 0; kk < 16; ++kk){
      float a[4], bb[4];
      #pragma unroll
      for (int i = 0; i < 4; ++i) a[i] = As[kk][ty + 16*i];
      #pragma unroll
      for (int j = 0; j < 4; ++j) bb[j] = Bs[kk][tx + 16*j];
      #pragma unroll
      for (int i = 0; i < 4; ++i)
        #pragma unroll
        for (int j = 0; j < 4; ++j) acc[i][j] = fmaf(a[i], bb[j], acc[i][j]);
    }
    __syncthreads();
  }
  for (int i = 0; i < 4; ++i){
    int gm = m0 + ty + 16*i; if (gm >= M) continue;
    for (int j = 0; j < 4; ++j){
      int gn = n0 + tx + 16*j; if (gn >= N) continue;
      C[(size_t)gm*N + gn] = acc[i][j] + bias[gn];
    }
  }
}

// ---------------- te GRU scan ----------------
__global__ __launch_bounds__(192) void k_te_scan(const float* __restrict__ xw, const float* __restrict__ Whh,
                 const float* __restrict__ bhh, float* __restrict__ X){
  int b = blockIdx.x; int tid = threadIdx.x;
  __shared__ float Wsh[TE3_*65];
  __shared__ float hs[64];
  __shared__ float gh[TE3_];
  for (int l = tid; l < TE3_*64; l += 192){ int j = l >> 6, f = l & 63; Wsh[j*65+f] = Whh[l]; }
  if (tid < 64) hs[tid] = 0.f;
  __syncthreads();
  for (int t = 0; t < T_; ++t){
    const float* xr = xw + ((size_t)b*T_ + t)*TE3_;
    float g = bhh[tid];
    #pragma unroll 8
    for (int f = 0; f < 64; ++f) g = fmaf(hs[f], Wsh[tid*65+f], g);
    gh[tid] = g;
    __syncthreads();
    if (tid < 64){
      float r = sigf(xr[tid] + gh[tid]);
      float z = sigf(xr[64+tid] + gh[64+tid]);
      float n = tanhf(xr[128+tid] + r*gh[128+tid]);
      float hn = (1.f - z)*n + z*hs[tid];
      hs[tid] = hn;
      X[((size_t)b*NT_ + N_ + t)*L_ + tid] = hn;
    }
    __syncthreads();
  }
}

// ---------------- X -> bf16 hi/lo (row-major + transposed, pads zeroed) ----------------
__global__ __launch_bounds__(256) void k_xbf(const float* __restrict__ X,
                 u16* __restrict__ Xbh, u16* __restrict__ Xbl,
                 u16* __restrict__ XTh, u16* __restrict__ XTl){
  __shared__ u16 th[32][33], tl[32][33];
  int b = blockIdx.z, i0 = blockIdx.x*32, f0 = blockIdx.y*32;
  int tx = threadIdx.x & 31, ty = threadIdx.x >> 5;
  for (int rr = ty; rr < 32; rr += 8){
    int i = i0 + rr, f = f0 + tx;
    float v = (i < NT_) ? X[((size_t)b*NT_ + i)*L_ + f] : 0.f;
    u16 hi = f2bf(v);
    u16 lo = f2bf(v - bf2f(hi));
    th[rr][tx] = hi; tl[rr][tx] = lo;
    Xbh[((size_t)b*NTP + i)*L_ + f] = hi;
    Xbl[((size_t)b*NTP + i)*L_ + f] = lo;
  }
  __syncthreads();
  for (int rr = ty; rr < 32; rr += 8){
    XTh[((size_t)b*L_ + f0 + rr)*NTP + i0 + tx] = th[tx][rr];
    XTl[((size_t)b*L_ + f0 + rr)*NTP + i0 + tx] = tl[tx][rr];
  }
}

// ---------------- adjacency (MFMA bf16 hi/lo): adj = tanh(relu(X X^T)+I) ----------------
__global__ __launch_bounds__(256) void k_adjb(const u16* __restrict__ Xbh, const u16* __restrict__ Xbl,
                                              u16* __restrict__ adjh, u16* __restrict__ adjl){
  int b = blockIdx.z, i0 = blockIdx.x*64, j0 = blockIdx.y*64;
  int tid = threadIdx.x, wv = tid >> 6, lane = tid & 63;
  const u16* Ah = Xbh + ((size_t)b*NTP + i0 + 16*wv + (lane & 15))*L_ + (lane >> 4)*8;
  const u16* Al = Xbl + ((size_t)b*NTP + i0 + 16*wv + (lane & 15))*L_ + (lane >> 4)*8;
  const u16* Bh = Xbh + ((size_t)b*NTP + j0 + (lane & 15))*L_ + (lane >> 4)*8;
  const u16* Bl = Xbl + ((size_t)b*NTP + j0 + (lane & 15))*L_ + (lane >> 4)*8;
  f32x4 chh[4], chl[4], clh[4];
  #pragma unroll
  for (int q = 0; q < 4; ++q){ chh[q] = (f32x4){0,0,0,0}; chl[q] = (f32x4){0,0,0,0}; clh[q] = (f32x4){0,0,0,0}; }
  #pragma unroll
  for (int kt = 0; kt < 2; ++kt){
    short8 ah = *(const short8*)(Ah + kt*32);
    short8 al = *(const short8*)(Al + kt*32);
    #pragma unroll
    for (int q = 0; q < 4; ++q){
      short8 bh = *(const short8*)(Bh + q*16*L_ + kt*32);
      short8 bl = *(const short8*)(Bl + q*16*L_ + kt*32);
      chh[q] = bmfma(ah, bh, chh[q]);
      chl[q] = bmfma(ah, bl, chl[q]);
      clh[q] = bmfma(al, bh, clh[q]);
    }
  }
  int ib = i0 + 16*wv + (lane >> 4)*4;
  int jb = j0 + (lane & 15);
  #pragma unroll
  for (int q = 0; q < 4; ++q){
    int j = jb + q*16;
    #pragma unroll
    for (int r = 0; r < 4; ++r){
      int i = ib + r;
      size_t idx = ((size_t)b*NTP + i)*NTP + j;
      if (i < NT_ && j < NT_){
        float v = tanhf(fmaxf(chh[q][r] + chl[q][r] + clh[q][r], 0.f) + (i == j ? 1.f : 0.f));
        u16 hi = f2bf(v);
        adjh[idx] = hi;
        adjl[idx] = f2bf(v - bf2f(hi));
      } else {
        adjh[idx] = 0; adjl[idx] = 0;
      }
    }
  }
}

// ---------------- fused GCN layer (MFMA bf16 hi/lo): Y = elu((adj@h)@W + b) ----------------
__global__ __launch_bounds__(256) void k_gcnm(const u16* __restrict__ adjh, const u16* __restrict__ adjl,
                 const u16* __restrict__ hTh, const u16* __restrict__ hTl,
                 const u16* __restrict__ WTh, const u16* __restrict__ WTl,
                 const float* __restrict__ bias,
                 float* __restrict__ Y, u16* __restrict__ YTh, u16* __restrict__ YTl){
  __shared__ u16 Tlh[64*72], Tll[64*72];
  int b = blockIdx.y, i0 = blockIdx.x*64;
  int tid = threadIdx.x, wv = tid >> 6, lane = tid & 63;
  // stage 1: T[i][f] = sum_j adj[i][j] h[j][f]
  const u16* Ah = adjh + ((size_t)b*NTP + i0 + 16*wv + (lane & 15))*NTP + (lane >> 4)*8;
  const u16* Al = adjl + ((size_t)b*NTP + i0 + 16*wv + (lane & 15))*NTP + (lane >> 4)*8;
  const u16* Bh = hTh + ((size_t)b*L_ + (lane & 15))*NTP + (lane >> 4)*8;
  const u16* Bl = hTl + ((size_t)b*L_ + (lane & 15))*NTP + (lane >> 4)*8;
  f32x4 thh[4], thl[4], tlh[4];
  #pragma unroll
  for (int q = 0; q < 4; ++q){ thh[q] = (f32x4){0,0,0,0}; thl[q] = (f32x4){0,0,0,0}; tlh[q] = (f32x4){0,0,0,0}; }
  #pragma unroll 2
  for (int kt = 0; kt < 28; ++kt){
    short8 ah = *(const short8*)(Ah + kt*32);
    short8 al = *(const short8*)(Al + kt*32);
    #pragma unroll
    for (int q = 0; q < 4; ++q){
      short8 bh = *(const short8*)(Bh + q*16*NTP + kt*32);
      short8 bl = *(const short8*)(Bl + q*16*NTP + kt*32);
      thh[q] = bmfma(ah, bh, thh[q]);
      thl[q] = bmfma(ah, bl, thl[q]);
      tlh[q] = bmfma(al, bh, tlh[q]);
    }
  }
  // T -> LDS bf16 hi/lo (rows m, cols f)
  {
    int mrow = 16*wv + (lane >> 4)*4;
    #pragma unroll
    for (int q = 0; q < 4; ++q)
      #pragma unroll
      for (int r = 0; r < 4; ++r){
        float v = thh[q][r] + thl[q][r] + tlh[q][r];
        u16 hi = f2bf(v);
        Tlh[(mrow + r)*72 + q*16 + (lane & 15)] = hi;
        Tll[(mrow + r)*72 + q*16 + (lane & 15)] = f2bf(v - bf2f(hi));
      }
  }
  __syncthreads();
  // stage 2: D2[i][g] = sum_f T[i][f] WT[g][f]
  const u16* A2h = Tlh + (16*wv + (lane & 15))*72 + (lane >> 4)*8;
  const u16* A2l = Tll + (16*wv + (lane & 15))*72 + (lane >> 4)*8;
  const u16* B2h = WTh + (lane & 15)*L_ + (lane >> 4)*8;
  const u16* B2l = WTl + (lane & 15)*L_ + (lane >> 4)*8;
  f32x4 ohh[4], ohl[4], olh[4];
  #pragma unroll
  for (int q = 0; q < 4; ++q){ ohh[q] = (f32x4){0,0,0,0}; ohl[q] = (f32x4){0,0,0,0}; olh[q] = (f32x4){0,0,0,0}; }
  #pragma unroll
  for (int kt = 0; kt < 2; ++kt){
    short8 a2h = *(const short8*)(A2h + kt*32);
    short8 a2l = *(const short8*)(A2l + kt*32);
    #pragma unroll
    for (int q = 0; q < 4; ++q){
      short8 b2h = *(const short8*)(B2h + q*16*L_ + kt*32);
      short8 b2l = *(const short8*)(B2l + q*16*L_ + kt*32);
      ohh[q] = bmfma(a2h, b2h, ohh[q]);
      ohl[q] = bmfma(a2h, b2l, ohl[q]);
      olh[q] = bmfma(a2l, b2h, olh[q]);
    }
  }
  __syncthreads();   // stage-2 LDS reads done; Tl* may be overwritten
  {
    int mrow = 16*wv + (lane >> 4)*4;
    #pragma unroll
    for (int q = 0; q < 4; ++q){
      int g = q*16 + (lane & 15);
      float bv = bias[g];
      #pragma unroll
      for (int r = 0; r < 4; ++r){
        int i = i0 + mrow + r;
        float v = eluf(ohh[q][r] + ohl[q][r] + olh[q][r] + bv);
        if (i < NT_ && Y) Y[((size_t)b*NT_ + i)*L_ + g] = v;
        u16 hi = 0, lo = 0;
        if (i < NT_){ hi = f2bf(v); lo = f2bf(v - bf2f(hi)); }
        Tlh[g*72 + mrow + r] = hi;
        Tll[g*72 + mrow + r] = lo;
      }
    }
  }
  __syncthreads();
  // coalesced YT write: 64 g-rows x 64 cols
  {
    int g = tid >> 2, c = tid & 3;
    uint4* dh = (uint4*)(YTh + ((size_t)b*L_ + g)*NTP + i0 + c*16);
    uint4* dl = (uint4*)(YTl + ((size_t)b*L_ + g)*NTP + i0 + c*16);
    const uint4* sh = (const uint4*)(Tlh + g*72 + c*16);
    const uint4* sl = (const uint4*)(Tll + g*72 + c*16);
    dh[0] = sh[0]; dh[1] = sh[1];
    dl[0] = sl[0]; dl[1] = sl[1];
  }
}

// ---------------- fr path: only output cols 160..167 needed ----------------
__global__ __launch_bounds__(192) void k_fr(const float* __restrict__ X, const float* __restrict__ W1,
                const float* __restrict__ b1, const float* __restrict__ W2,
                const float* __restrict__ b2, float* __restrict__ nout8){
  int bn = blockIdx.x; int b = bn / N_, n = bn % N_;
  int tid = threadIdx.x;
  __shared__ float xs[64];
  __shared__ float t1[T_];
  __shared__ float part[24*8];
  if (tid < 64) xs[tid] = X[((size_t)b*NT_+n)*L_+tid];
  __syncthreads();
  if (tid < T_){
    float a = b1[tid];
    #pragma unroll 8
    for (int ff = 0; ff < 64; ++ff) a = fmaf(xs[ff], W1[ff*T_+tid], a);
    t1[tid] = eluf(a);
  }
  __syncthreads();
  int c = tid & 7, p = tid >> 3;
  float s = 0.f;
  for (int ff = p; ff < T_; ff += 24) s = fmaf(t1[ff], W2[ff*T_ + 160 + c], s);
  part[p*8 + c] = s;
  __syncthreads();
  if (tid < 8){
    float a = b2[160 + tid];
    #pragma unroll
    for (int q = 0; q < 24; ++q) a += part[q*8 + tid];
    nout8[((size_t)bn)*8 + tid] = a;
  }
}

// ---------------- gather Xt into (T, B, 64) layout ----------------
__global__ __launch_bounds__(256) void k_xtbuf(const float* __restrict__ X, float* __restrict__ XtBuf){
  int idx = blockIdx.x*256 + threadIdx.x;
  if (idx >= T_*B_*L_) return;
  int f = idx & 63; int tb = idx >> 6; int bb = tb & 31; int t = tb >> 5;
  XtBuf[idx] = X[((size_t)bb*NT_ + N_ + t)*L_ + f];
}

// ---------------- persistent MFMA tr-GRU scan ----------------
// Cross-block h + flags move via RELAXED agent-scope atomics (sc0/sc1
// cache-bypass to LLC) -> NO L2 writeback/invalidate ops in the loop.
// Ordering: wave0 `s_waitcnt vmcnt(0)` between h store and flag store.
// Barrier: lanes 0..44 poll the 45 producer flags of this batch-half.
__global__ __launch_bounds__(192) void k_tr_scan(
    const u16* __restrict__ WhhB,  // (2148, 716) bf16
    const float* __restrict__ bhh,
    const float* __restrict__ xw,  // (5376, 2148) incl. bih
    u16* __restrict__ hb0, u16* __restrict__ hb1,  // (32, 720) bf16
    float* __restrict__ tout8,
    int* __restrict__ flags){
  __shared__ u16 w_lds[48*WSTR];
  __shared__ u16 h_lds[16*WSTR];
  __shared__ float g_lds[2*256];
  __shared__ float xw_lds[2][16*48];
  const int tid = threadIdx.x;
  const int wv = tid >> 6, lane = tid & 63;
  const int cb = blockIdx.x >> 1, hhalf = blockIdx.x & 1;
  const int k0 = cb*16, b0 = hhalf*16;

  // xw prefetch for step 0 into buffer 0
  {
    int row = tid / 12, c = tid % 12;
    int g = c >> 2, koff = (c & 3)*4;
    *(f32x4*)(&xw_lds[0][row*48 + g*16 + koff]) =
      *(const f32x4*)(xw + (size_t)(b0 + row)*TR3_ + g*TRH_ + k0 + koff);
  }
  // zero h_lds pad cols [720..744)
  for (int o = tid; o < 16*24; o += 192){
    int n = o / 24, c = o - n*24;
    h_lds[n*WSTR + 720 + c] = 0;
  }
  // stage weights bf16 -> LDS; rows r = gate*16+m, zero-pad cols >=716
  for (int r = 0; r < 48; ++r){
    int g = r >> 4, m = r & 15, k = k0 + m;
    bool kv = (k < TRH_);
    const uint2* src = (const uint2*)(WhhB + (size_t)(g*TRH_ + (kv ? k : 0))*TRH_);
    uint2* dst = (uint2*)(w_lds + r*WSTR);
    uint2 zz; zz.x = 0; zz.y = 0;
    for (int o = tid; o < 186; o += 192)
      dst[o] = (kv && o < 179) ? src[o] : zz;
  }
  const u16* arow = w_lds + (size_t)(wv*16 + (lane & 15))*WSTR + (lane >> 4)*8;
  const u16* brow = h_lds + (size_t)(lane & 15)*WSTR + (lane >> 4)*8;

  const int mb = (lane >> 4)*4;
  const int kx = k0 + mb;
  const bool kval = (kx < TRH_);
  const int bx = b0 + (lane & 15);
  f32x4 hp = {0.f, 0.f, 0.f, 0.f};
  f32x4 br4 = {0,0,0,0}, bz4 = {0,0,0,0}, bn4 = {0,0,0,0};
  if (wv == 0){
    int kc = kval ? kx : 0;
    br4 = *(const f32x4*)(bhh + kc);
    bz4 = *(const f32x4*)(bhh + TRH_ + kc);
    bn4 = *(const f32x4*)(bhh + 2*TRH_ + kc);
  }
  __syncthreads();

  for (int t = 0; t < T_; ++t){
    const u16* hcur = (t & 1) ? hb1 : hb0;
    u16* hnxt = (t & 1) ? hb0 : hb1;
    // wait for all 45 producers of this batch-half to have finished step t-1
    if (tid < 45){
      const int* fp = flags + (tid*2 + hhalf)*16;
      while (__hip_atomic_load(fp, __ATOMIC_RELAXED, __HIP_MEMORY_SCOPE_AGENT) < t){}
    }
    __syncthreads();   // A: h_{t-1} globally visible; prev-step LDS consumers done
    // stage h slice: 16 rows x 180 u64 (cache-bypass loads -> LLC)
    for (int o = tid; o < 2880; o += 192){
      int n = o / 180, c = o - n*180;
      u64 v = __hip_atomic_load((const u64*)(hcur + (size_t)(b0 + n)*HSTR) + c,
                                __ATOMIC_RELAXED, __HIP_MEMORY_SCOPE_AGENT);
      *(u64*)(h_lds + n*WSTR + c*4) = v;
    }
    __syncthreads();   // B: h_lds ready
    // MFMA over 23 k-tiles, 4 independent chains
    f32x4 a0={0,0,0,0}, a1={0,0,0,0}, a2={0,0,0,0}, a3={0,0,0,0};
    for (int kt = 0; kt < 20; kt += 4){
      a0 = bmfma(*(const short8*)(arow + kt*32),     *(const short8*)(brow + kt*32),     a0);
      a1 = bmfma(*(const short8*)(arow + (kt+1)*32), *(const short8*)(brow + (kt+1)*32), a1);
      a2 = bmfma(*(const short8*)(arow + (kt+2)*32), *(const short8*)(brow + (kt+2)*32), a2);
      a3 = bmfma(*(const short8*)(arow + (kt+3)*32), *(const short8*)(brow + (kt+3)*32), a3);
    }
    a0 = bmfma(*(const short8*)(arow + 20*32), *(const short8*)(brow + 20*32), a0);
    a1 = bmfma(*(const short8*)(arow + 21*32), *(const short8*)(brow + 21*32), a1);
    a2 = bmfma(*(const short8*)(arow + 22*32), *(const short8*)(brow + 22*32), a2);
    f32x4 acc = (a0 + a1) + (a2 + a3);
    if (wv){
      #pragma unroll
      for (int r = 0; r < 4; ++r) g_lds[(wv-1)*256 + lane*4 + r] = acc[r];
    }
    __syncthreads();   // C: gate partials exchanged
    if (wv == 0 && kval){
      const float* xb = &xw_lds[t & 1][(lane & 15)*48];
      float hnew[4];
      #pragma unroll
      for (int r = 0; r < 4; ++r){
        float rg = sigf(xb[mb + r] + acc[r] + br4[r]);
        float zg = sigf(xb[16 + mb + r] + g_lds[lane*4 + r] + bz4[r]);
        float ng = tanhf(xb[32 + mb + r] + rg*(g_lds[256 + lane*4 + r] + bn4[r]));
        hnew[r] = (1.f - zg)*ng + zg*hp[r];
        hp[r] = hnew[r];
      }
      u64 pk = (u64)((unsigned)f2bf(hnew[0]) | ((unsigned)f2bf(hnew[1]) << 16))
             | ((u64)((unsigned)f2bf(hnew[2]) | ((unsigned)f2bf(hnew[3]) << 16)) << 32);
      __hip_atomic_store((u64*)(hnxt + (size_t)bx*HSTR + kx), pk,
                         __ATOMIC_RELAXED, __HIP_MEMORY_SCOPE_AGENT);
      if (t >= 160){
        #pragma unroll
        for (int r = 0; r < 4; ++r)
          tout8[(size_t)(bx*TRH_ + kx + r)*8 + (t - 160)] = hnew[r];
      }
    }
    if (wv == 0){
      asm volatile("s_waitcnt vmcnt(0)" ::: "memory");   // h stores at LLC
      if (lane == 0)
        __hip_atomic_store(flags + blockIdx.x*16, t + 1,
                           __ATOMIC_RELAXED, __HIP_MEMORY_SCOPE_AGENT);
    }
    // prefetch xw for t+1 into the other buffer (overlaps gates/poll)
    if (t + 1 < T_){
      int row = tid / 12, c = tid % 12;
      int g = c >> 2, koff = (c & 3)*4;
      *(f32x4*)(&xw_lds[(t + 1) & 1][row*48 + g*16 + koff]) =
        *(const f32x4*)(xw + (size_t)((t+1)*32 + b0 + row)*TR3_ + g*TRH_ + k0 + koff);
    }
  }
}

// ---------------- fused TCN tail ----------------
__global__ __launch_bounds__(256) void k_tcn(const float* __restrict__ nout8, const float* __restrict__ tout8,
                 const float* __restrict__ x,
                 const float* __restrict__ W0, const float* __restrict__ b0,
                 const float* __restrict__ W1, const float* __restrict__ b1,
                 const float* __restrict__ W2, const float* __restrict__ b2,
                 const float* __restrict__ oW, const float* __restrict__ ob,
                 float* __restrict__ out){
  __shared__ float w0s[96], b0s[16], w1s[512], b1s[16], w2s[512], b2s[16], ows[16], obs;
  int tid = threadIdx.x;
  for (int l = tid; l < 96; l += 256) w0s[l] = W0[l];
  for (int l = tid; l < 512; l += 256){ w1s[l] = W1[l]; w2s[l] = W2[l]; }
  if (tid < 16){ b0s[tid]=b0[tid]; b1s[tid]=b1[tid]; b2s[tid]=b2[tid]; ows[tid]=oW[tid]; }
  if (tid == 0) obs = ob[0];
  __syncthreads();
  int idx = blockIdx.x*256 + tid;
  if (idx >= B_*N_) return;
  int b = idx / N_, n = idx % N_;
  float s0[8], s1[8], s2[8];
  #pragma unroll
  for (int i = 0; i < 8; ++i){
    s0[i] = nout8[(size_t)idx*8 + i];
    s1[i] = tout8[(size_t)idx*8 + i];
    s2[i] = x[((size_t)b*N_ + n)*T_ + 160 + i];
  }
  float h1[16][4];
  #pragma unroll
  for (int c = 0; c < 16; ++c)
    #pragma unroll
    for (int q = 0; q < 4; ++q){
      int tt = 2*q + 1;
      float v = b0s[c]
        + w0s[c*6+0]*s0[tt-1] + w0s[c*6+1]*s0[tt]
        + w0s[c*6+2]*s1[tt-1] + w0s[c*6+3]*s1[tt]
        + w0s[c*6+4]*s2[tt-1] + w0s[c*6+5]*s2[tt];
      h1[c][q] = eluf(v);
    }
  float h2[16][2];
  #pragma unroll
  for (int c = 0; c < 16; ++c){
    float v3 = b1s[c], v7 = b1s[c];
    #pragma unroll
    for (int i2 = 0; i2 < 16; ++i2){
      v3 += w1s[c*32+i2*2]*h1[i2][0] + w1s[c*32+i2*2+1]*h1[i2][1];
      v7 += w1s[c*32+i2*2]*h1[i2][2] + w1s[c*32+i2*2+1]*h1[i2][3];
    }
    h2[c][0] = eluf(v3); h2[c][1] = eluf(v7);
  }
  float o = obs;
  #pragma unroll
  for (int c = 0; c < 16; ++c){
    float v = b2s[c];
    #pragma unroll
    for (int i2 = 0; i2 < 16; ++i2)
      v += w2s[c*32+i2*2]*h2[i2][0] + w2s[c*32+i2*2+1]*h2[i2][1];
    o += ows[c]*eluf(v);
  }
  out[idx] = o;
}

extern "C" void kernel_launch(void* const* d_in, const int* in_sizes, int n_in,
                              void* d_out, int out_size, void* d_ws, size_t ws_size,
                              hipStream_t stream){
  const float* x       = (const float*)d_in[0];
  const float* mark    = (const float*)d_in[1];
  const float* se_emb  = (const float*)d_in[2];
  const float* se_W1   = (const float*)d_in[3];
  const float* se_b1   = (const float*)d_in[4];
  const float* se_W2   = (const float*)d_in[5];
  const float* se_b2   = (const float*)d_in[6];
  const float* te_emb  = (const float*)d_in[7];
  const float* te_Wih  = (const float*)d_in[8];
  const float* te_Whh  = (const float*)d_in[9];
  const float* te_bih  = (const float*)d_in[10];
  const float* te_bhh  = (const float*)d_in[11];
  const float* gcn_W   = (const float*)d_in[12];
  const float* gcn_b   = (const float*)d_in[13];
  const float* fr_W1   = (const float*)d_in[14];
  const float* fr_b1   = (const float*)d_in[15];
  const float* fr_W2   = (const float*)d_in[16];
  const float* fr_b2   = (const float*)d_in[17];
  const float* tr_Wih  = (const float*)d_in[18];
  const float* tr_Whh  = (const float*)d_in[19];
  const float* tr_bih  = (const float*)d_in[20];
  const float* tr_bhh  = (const float*)d_in[21];
  const float* tcn_W0  = (const float*)d_in[22];
  const float* tcn_b0  = (const float*)d_in[23];
  const float* tcn_W1  = (const float*)d_in[24];
  const float* tcn_b1  = (const float*)d_in[25];
  const float* tcn_W2  = (const float*)d_in[26];
  const float* tcn_b2  = (const float*)d_in[27];
  const float* out_W   = (const float*)d_in[28];
  const float* out_b   = (const float*)d_in[29];
  float* out = (float*)d_out;
  (void)in_sizes; (void)n_in; (void)out_size; (void)ws_size;

  char* ws = (char*)d_ws;
  size_t off = 0;
  auto alloc = [&](size_t bytes)->void*{
    void* p = (void*)(ws + off); off += (bytes + 255) & ~(size_t)255; return p; };
  float* X       = (float*)alloc((size_t)B_*NT_*L_*4);
  u16*   adjh    = (u16*)  alloc((size_t)B_*NTP*NTP*2);   // 51.4MB
  u16*   adjl    = (u16*)  alloc((size_t)B_*NTP*NTP*2);   // 51.4MB
  float* WihT_tr = (float*)alloc((size_t)L_*TR3_*4);
  float* XtBuf   = (float*)alloc((size_t)T_*B_*L_*4);
  u16*   WhhB    = (u16*)  alloc((size_t)TR3_*TRH_*2);
  u16*   Xbh     = (u16*)  alloc((size_t)B_*NTP*L_*2);
  u16*   Xbl     = (u16*)  alloc((size_t)B_*NTP*L_*2);
  u16*   hTah    = (u16*)  alloc((size_t)B_*L_*NTP*2);
  u16*   hTal    = (u16*)  alloc((size_t)B_*L_*NTP*2);
  u16*   hTbh    = (u16*)  alloc((size_t)B_*L_*NTP*2);
  u16*   hTbl    = (u16*)  alloc((size_t)B_*L_*NTP*2);
  u16*   WTh     = (u16*)  alloc((size_t)4*4096*2);
  u16*   WTl     = (u16*)  alloc((size_t)4*4096*2);
  u16*   hb0     = (u16*)  alloc((size_t)B_*HSTR*2);
  u16*   hb1     = (u16*)  alloc((size_t)B_*HSTR*2);
  int*   flags   = (int*)  alloc(8192);
  float* nout8   = (float*)alloc((size_t)B_*N_*8*4);
  float* tout8   = (float*)alloc((size_t)B_*N_*8*4);
  // aliases: te buffers live only BEFORE the GCN (inside adjh);
  //          xw is written only AFTER the GCN (inside adjl)
  float* te_in   = (float*)adjh;                            // 16,171,008 B
  float* te_xw   = (float*)((char*)adjh + 16171008);        //  4,128,768 B
  float* WihT_te = (float*)((char*)adjh + 20299776);        //    577,536 B
  float* xw      = (float*)adjl;                            // 46,190,592 B

  hipMemsetAsync(hb0, 0, (size_t)B_*HSTR*2, stream);
  hipMemsetAsync(hb1, 0, (size_t)B_*HSTR*2, stream);
  hipMemsetAsync(flags, 0, 8192, stream);

  // weight prep
  k_whhbf<<<(TR3_*TRH_/4 + 255)/256, 256, 0, stream>>>(tr_Whh, WhhB, TR3_*TRH_/4);
  k_wtb<<<4, 256, 0, stream>>>(gcn_W, WTh, WTl);
  k_transpose<<<dim3(24,6),256,0,stream>>>(te_Wih, WihT_te, TE3_, GIN_);
  k_transpose<<<dim3(2,68),256,0,stream>>>(tr_Wih, WihT_tr, TR3_, L_);
  // SE path
  k_se<<<B_*N_,64,0,stream>>>(x, se_emb, se_W1, se_b1, se_W2, se_b2, X);
  // te path
  k_tein_x<<<dim3(23,6,B_),256,0,stream>>>(x, te_in);
  k_tein_rest<<<(B_*T_*36+255)/256,256,0,stream>>>(mark, te_emb, te_in);
  k_gemm_bias<<<dim3(84,3),256,0,stream>>>(te_in, WihT_te, te_bih, te_xw, B_*T_, TE3_, GIN_);
  k_te_scan<<<B_,192,0,stream>>>(te_xw, te_Whh, te_bhh, X);
  // GCN (MFMA bf16 hi/lo)
  for (int i = 0; i < 2; ++i){
    k_xbf<<<dim3(28,2,B_),256,0,stream>>>(X, Xbh, Xbl, hTah, hTal);
    k_adjb<<<dim3(14,14,B_),256,0,stream>>>(Xbh, Xbl, adjh, adjl);
    k_gcnm<<<dim3(14,B_),256,0,stream>>>(adjh, adjl, hTah, hTal,
        WTh + (i*2+0)*4096, WTl + (i*2+0)*4096, gcn_b + (i*2+0)*64, nullptr, hTbh, hTbl);
    k_gcnm<<<dim3(14,B_),256,0,stream>>>(adjh, adjl, hTbh, hTbl,
        WTh + (i*2+1)*4096, WTl + (i*2+1)*4096, gcn_b + (i*2+1)*64, X, hTah, hTal);
  }
  // fr path
  k_fr<<<B_*N_,192,0,stream>>>(X, fr_W1, fr_b1, fr_W2, fr_b2, nout8);
  // tr GRU: input projection, then persistent MFMA scan
  k_xtbuf<<<(T_*B_*L_+255)/256,256,0,stream>>>(X, XtBuf);
  k_gemm_bias<<<dim3(84,34),256,0,stream>>>(XtBuf, WihT_tr, tr_bih, xw, B_*T_, TR3_, L_);
  k_tr_scan<<<TRBLKS,192,0,stream>>>(WhhB, tr_bhh, xw, hb0, hb1, tout8, flags);
  // fused TCN tail
  k_tcn<<<(B_*N_+255)/256,256,0,stream>>>(nout8, tout8, x,
      tcn_W0, tcn_b0, tcn_W1, tcn_b1, tcn_W2, tcn_b2, out_W, out_b, out);
}